// Round 14
// baseline (3094.701 us; speedup 1.0000x reference)
//
#include <hip/hip_runtime.h>
#include <stdint.h>

typedef unsigned short u16;
typedef __attribute__((ext_vector_type(4))) float f32x4;
typedef __attribute__((ext_vector_type(8))) __bf16 bf16x8;

#define NT 6144     // B*T
#define TT 192
#define PRELU_A 0.25f

__device__ __forceinline__ u16 f2bf(float f) {
  unsigned u = __float_as_uint(f);
  u += 0x7fffu + ((u >> 16) & 1u);
  return (u16)(u >> 16);
}
__device__ __forceinline__ float bf2f(u16 u) {
  return __uint_as_float(((unsigned)u) << 16);
}

__device__ __forceinline__ void gload16(const u16* g, __bf16* l) {
  auto* l3 = reinterpret_cast<__attribute__((address_space(3))) __bf16*>(
      reinterpret_cast<uintptr_t>(l));
  const auto* g1 = reinterpret_cast<const __attribute__((address_space(1))) u16*>(
      reinterpret_cast<uintptr_t>(g));
  __builtin_amdgcn_global_load_lds(g1, l3, 16, 0, 0);
}

// XCD-contiguous (m204 bijective) + supertile decode.
// Work order: chunks of CX bx-panels; within a chunk, bx fastest, by outer.
// CX = gridX/8 when divisible -> each XCD slab == one chunk: CX A-panels stay
// L2-resident across ALL by, and each B-panel is read exactly once per XCD.
// (R13 PMC: CX=1 order re-streamed B per bx -> F1 FETCH 152MB vs ~21 ideal.)
__device__ __forceinline__ void xcd_remap(int& bx, int& by)
{
  const int gx = gridDim.x, gy = gridDim.y;
  const int nwg = gx * gy;
  const int f = blockIdx.y * gx + blockIdx.x;
  const int q = nwg >> 3, r = nwg & 7;
  const int xcd = f & 7, s = f >> 3;
  const int w = (xcd < r ? xcd*(q+1) : r*(q+1) + (xcd-r)*q) + s;
  const int CX = ((gx & 7) == 0) ? (gx >> 3) : 1;
  const int per = gy * CX;
  const int c = w / per, rr = w - c*per;
  bx = c*CX + (rr % CX);
  by = rr / CX;
}

// ---------------- transpose f32 [K,N] -> bf16 [Np,Kp] (zero-padded) ----------
__global__ __launch_bounds__(256)
void transpose_bf16(const float* __restrict__ src, u16* __restrict__ dst,
                    int K, int N, int Kp, int Np, long sstride, long dstride)
{
  src += (long)blockIdx.z * sstride;
  dst += (long)blockIdx.z * dstride;
  __shared__ float tile[64][65];
  const int kt = blockIdx.y * 64, nt = blockIdx.x * 64;
  #pragma unroll
  for (int i = 0; i < 16; ++i) {
    int idx = threadIdx.x + i*256;
    int kl = idx >> 6, nl = idx & 63;
    int k = kt + kl, n = nt + nl;
    tile[kl][nl] = (k < K && n < N) ? src[(long)k*N + n] : 0.f;
  }
  __syncthreads();
  #pragma unroll
  for (int i = 0; i < 16; ++i) {
    int idx = threadIdx.x + i*256;
    int nl = idx >> 6, kl = idx & 63;
    int n = nt + nl, k = kt + kl;
    if (n < Np && k < Kp) dst[(long)n*Kp + k] = f2bf(tile[kl][nl]);
  }
}

// ---------------- shared epilogue (COMPILE-TIME MR/HM — rule #20) ------------
template<int MR, int HM>
__device__ __forceinline__ void epilogue_store(
    f32x4 (&acc)[MR][4], long arow0, long brow0, int wm, int wn, int lane,
    const float* bias, int biasN,
    float* Cf, int ldc, int Nf, int accum,
    u16* Cb, int ldcb, int Nb, int act)
{
  const int rbase = wm*HM + ((lane >> 4) << 2);
  const int cbase = wn*64 + (lane & 15);
  #pragma unroll
  for (int m = 0; m < MR; ++m) {
    #pragma unroll
    for (int n = 0; n < 4; ++n) {
      const long gcol = brow0 + cbase + n*16;
      const float bv = (bias && gcol < biasN) ? bias[gcol] : 0.f;
      #pragma unroll
      for (int r = 0; r < 4; ++r) {
        const long grow = arow0 + rbase + m*16 + r;
        float v = acc[m][n][r] + bv;
        if (act == 1) v = fmaxf(v, 0.f);
        else if (act == 2) v = (v >= 0.f) ? v : PRELU_A * v;
        if (Cf && gcol < Nf) {
          const long idx = grow * (long)ldc + gcol;
          Cf[idx] = accum ? (Cf[idx] + v) : v;
        }
        if (Cb && gcol < Nb) Cb[grow * (long)ldcb + gcol] = f2bf(v);
      }
    }
  }
}

// ---------------- 64x128 bf16 GEMM, BK=64, ring-2 counted-vmcnt (R9/R11) -----
__global__ __launch_bounds__(256, 3)
void gemm64(const u16* __restrict__ A, const u16* __restrict__ Bt,
            const float* __restrict__ bias, int biasN,
            float* __restrict__ Cf, int ldc, int Nf, int accum,
            u16* __restrict__ Cb, int ldcb, int Nb,
            int K, int act)
{
  __shared__ __bf16 As[2*64*64];
  __shared__ __bf16 Bs[2*128*64];
  const int tid = threadIdx.x;
  const int wid = tid >> 6;
  const int lane = tid & 63;
  const int wm = wid >> 1, wn = wid & 1;
  int bx, by; xcd_remap(bx, by);
  const long arow0 = (long)bx * 64;
  const long brow0 = (long)by * 128;
  const int lr  = lane >> 3;
  const int lko = ((lane & 7) ^ (lane >> 3)) << 3;

  f32x4 acc[2][4];
  #pragma unroll
  for (int m = 0; m < 2; ++m)
    #pragma unroll
    for (int n = 0; n < 4; ++n) acc[m][n] = (f32x4)0.f;

  const int aro = lane & 15;
  const int g = lane >> 4;

  auto stage = [&](int buf, int kt) {
    #pragma unroll
    for (int c = wid; c < 24; c += 4) {
      if (c < 8) gload16(A + (arow0 + c*8 + lr)*K + kt + lko, As + buf*(64*64) + c*512);
      else       gload16(Bt + (brow0 + (c-8)*8 + lr)*K + kt + lko,
                         Bs + buf*(128*64) + (c-8)*512);
    }
  };

  const int nt = K >> 6;
  stage(0, 0);
  for (int t = 0; t < nt; ++t) {
    if (t + 1 < nt) {
      stage((t+1) & 1, (t+1) << 6);
      asm volatile("s_waitcnt vmcnt(6)" ::: "memory");
    } else {
      asm volatile("s_waitcnt vmcnt(0)" ::: "memory");
    }
    __builtin_amdgcn_s_barrier();
    asm volatile("" ::: "memory");
    const __bf16* Ab = As + (t&1)*(64*64);
    const __bf16* Bb = Bs + (t&1)*(128*64);
    #pragma unroll
    for (int kk = 0; kk < 2; ++kk) {
      bf16x8 af[2], bfv[4];
      #pragma unroll
      for (int m = 0; m < 2; ++m) {
        const int R = wm*32 + m*16 + aro;
        af[m] = *(const bf16x8*)(Ab + R*64 + (((kk*4 + g) ^ (R & 7)) << 3));
      }
      #pragma unroll
      for (int n = 0; n < 4; ++n) {
        const int R = wn*64 + n*16 + aro;
        bfv[n] = *(const bf16x8*)(Bb + R*64 + (((kk*4 + g) ^ (R & 7)) << 3));
      }
      #pragma unroll
      for (int m = 0; m < 2; ++m)
        #pragma unroll
        for (int n = 0; n < 4; ++n)
          acc[m][n] = __builtin_amdgcn_mfma_f32_16x16x32_bf16(af[m], bfv[n], acc[m][n], 0, 0, 0);
    }
    asm volatile("" ::: "memory");
    __builtin_amdgcn_s_barrier();    // readers done before next stage overwrites
  }
  epilogue_store<2,32>(acc, arow0, brow0, wm, wn, lane,
                       bias, biasN, Cf, ldc, Nf, accum, Cb, ldcb, Nb, act);
}

// ---------------- 128x128 bf16 GEMM, BK=32, ring-2, 32KB LDS (R13) -----------
__global__ __launch_bounds__(256, 4)
void gemm128(const u16* __restrict__ A, const u16* __restrict__ Bt,
             const float* __restrict__ bias, int biasN,
             float* __restrict__ Cf, int ldc, int Nf, int accum,
             u16* __restrict__ Cb, int ldcb, int Nb,
             int K, int act)
{
  __shared__ __bf16 As[2*128*32];
  __shared__ __bf16 Bs[2*128*32];
  const int tid = threadIdx.x;
  const int wid = tid >> 6;
  const int lane = tid & 63;
  const int wm = wid >> 1, wn = wid & 1;
  int bx, by; xcd_remap(bx, by);
  const long arow0 = (long)bx * 128;
  const long brow0 = (long)by * 128;
  const int srow = lane >> 2;
  const int skoff = ((lane & 3) ^ ((lane >> 3) & 3)) << 3;

  f32x4 acc[4][4];
  #pragma unroll
  for (int m = 0; m < 4; ++m)
    #pragma unroll
    for (int n = 0; n < 4; ++n) acc[m][n] = (f32x4)0.f;

  const int aro = lane & 15;
  const int g = lane >> 4;

  auto stage = [&](int buf, int kt) {
    #pragma unroll
    for (int c = wid; c < 16; c += 4) {
      if (c < 8) gload16(A + (arow0 + c*16 + srow)*K + kt + skoff, As + buf*4096 + c*512);
      else       gload16(Bt + (brow0 + (c-8)*16 + srow)*K + kt + skoff,
                         Bs + buf*4096 + (c-8)*512);
    }
  };

  const int nt = K >> 5;
  stage(0, 0);
  for (int t = 0; t < nt; ++t) {
    if (t + 1 < nt) {
      stage((t+1) & 1, (t+1) << 5);
      asm volatile("s_waitcnt vmcnt(4)" ::: "memory");
    } else {
      asm volatile("s_waitcnt vmcnt(0)" ::: "memory");
    }
    __builtin_amdgcn_s_barrier();
    asm volatile("" ::: "memory");
    const __bf16* Ab = As + (t&1)*4096;
    const __bf16* Bb = Bs + (t&1)*4096;
    bf16x8 af[4], bfv[4];
    #pragma unroll
    for (int m = 0; m < 4; ++m) {
      const int R = wm*64 + m*16 + aro;
      af[m] = *(const bf16x8*)(Ab + R*32 + ((g ^ ((R >> 1) & 3)) << 3));
    }
    #pragma unroll
    for (int n = 0; n < 4; ++n) {
      const int R = wn*64 + n*16 + aro;
      bfv[n] = *(const bf16x8*)(Bb + R*32 + ((g ^ ((R >> 1) & 3)) << 3));
    }
    #pragma unroll
    for (int m = 0; m < 4; ++m)
      #pragma unroll
      for (int n = 0; n < 4; ++n)
        acc[m][n] = __builtin_amdgcn_mfma_f32_16x16x32_bf16(af[m], bfv[n], acc[m][n], 0, 0, 0);
    asm volatile("" ::: "memory");
    __builtin_amdgcn_s_barrier();    // readers done before next stage overwrites
  }
  epilogue_store<4,64>(acc, arow0, brow0, wm, wn, lane,
                       bias, biasN, Cf, ldc, Nf, accum, Cb, ldcb, Nb, act);
}

// --- MoE blend (2 half-buffers, H=1024): out = prelu(sum_e gate_e * C_e) ----
__global__ __launch_bounds__(256)
void moe_blend2(const u16* __restrict__ C0, const u16* __restrict__ C1,
                const float* __restrict__ gate, u16* __restrict__ outb)
{
  const long idx = (long)blockIdx.x*256 + threadIdx.x;   // float4 over [NT,1024]
  if (idx >= (long)NT*256) return;
  const long t = idx >> 8;
  const int h = (int)(idx & 255) << 2;
  float sx = 0.f, sy = 0.f, sz = 0.f, sw = 0.f;
  #pragma unroll
  for (int j = 0; j < 4; ++j) {
    const float gv = gate[t*8 + j];
    const ushort4 c4 = *(const ushort4*)(C0 + t*4096 + j*1024 + h);
    sx += gv * bf2f(c4.x); sy += gv * bf2f(c4.y);
    sz += gv * bf2f(c4.z); sw += gv * bf2f(c4.w);
  }
  #pragma unroll
  for (int j = 0; j < 4; ++j) {
    const float gv = gate[t*8 + 4 + j];
    const ushort4 c4 = *(const ushort4*)(C1 + t*4096 + j*1024 + h);
    sx += gv * bf2f(c4.x); sy += gv * bf2f(c4.y);
    sz += gv * bf2f(c4.z); sw += gv * bf2f(c4.w);
  }
  sx = (sx >= 0.f) ? sx : PRELU_A * sx;
  sy = (sy >= 0.f) ? sy : PRELU_A * sy;
  sz = (sz >= 0.f) ? sz : PRELU_A * sz;
  sw = (sw >= 0.f) ? sw : PRELU_A * sw;
  ushort4 o; o.x = f2bf(sx); o.y = f2bf(sy); o.z = f2bf(sz); o.w = f2bf(sw);
  *(ushort4*)(outb + t*1024 + h) = o;
}

// --- MoE final blend (level 2, H=256, 8 experts contiguous) -> f32 out -------
__global__ __launch_bounds__(256)
void moe_blend_out(const u16* __restrict__ C, const float* __restrict__ gate,
                   float* __restrict__ outf)
{
  const long idx = (long)blockIdx.x*256 + threadIdx.x;   // float4 over [NT,256]
  if (idx >= (long)NT*64) return;
  const long t = idx >> 6;
  const int h = (int)(idx & 63) << 2;
  float sx = 0.f, sy = 0.f, sz = 0.f, sw = 0.f;
  #pragma unroll
  for (int j = 0; j < 8; ++j) {
    const float gv = gate[t*8 + j];
    const ushort4 c4 = *(const ushort4*)(C + t*2048 + j*256 + h);
    sx += gv * bf2f(c4.x); sy += gv * bf2f(c4.y);
    sz += gv * bf2f(c4.z); sw += gv * bf2f(c4.w);
  }
  float4 o; o.x = sx; o.y = sy; o.z = sz; o.w = sw;
  ((float4*)(outf + t*256))[h >> 2] = o;
}

// ---------------- small helper kernels --------------------------------------
__global__ __launch_bounds__(256)
void build_xin(const float* __restrict__ motion, const float* __restrict__ phase,
               u16* __restrict__ xin)   // [NT, 320] zero-padded
{
  const long idx = (long)blockIdx.x*256 + threadIdx.x;
  if (idx >= (long)NT*320) return;
  const int c = (int)(idx % 320);
  const long row = idx / 320;
  const int t = (int)(row % TT);
  const bool dm = (t < 10) || (t == TT-1);
  float v;
  if (c < 256)       v = dm ? motion[row*256 + c] : 0.f;
  else if (c == 256) v = dm ? 1.f : 0.f;
  else if (c < 273)  v = dm ? phase[row*16 + (c-257)] : 0.f;
  else               v = 0.f;
  xin[idx] = f2bf(v);
}

__global__ __launch_bounds__(256)
void build_kp(u16* __restrict__ kp)    // [256, 64] zero-padded
{
  const int idx = blockIdx.x*256 + threadIdx.x;
  if (idx >= 256*64) return;
  const int r = idx / 64, c = idx % 64;
  float v = 0.f;
  if (r < TT) {
    if (c == 0) v = (float)(r - 9);
    else if (c == 1) v = (float)(TT-1 - r);
  }
  kp[idx] = f2bf(v);
}

__global__ __launch_bounds__(256)
void cat_kv_bias(const float* __restrict__ bk, const float* __restrict__ bv,
                 float* __restrict__ kvb)   // [8][2048]
{
  const int idx = blockIdx.x*256 + threadIdx.x;
  if (idx >= 8*2048) return;
  const int l = idx >> 11, c = idx & 2047;
  kvb[idx] = (c < 1024) ? bk[l*1024 + c] : bv[l*1024 + c - 1024];
}

__global__ __launch_bounds__(64)
void relpos(const float* __restrict__ W1, const float* __restrict__ b1,
            const float* __restrict__ W2, const float* __restrict__ b2,
            float* __restrict__ rel)
{
  const int r = blockIdx.x;      // 0..383 (rows >=383 zeroed, never read)
  const int d = threadIdx.x;
  __shared__ float h[64];
  const float rp = (float)(r - (TT-1));
  float hv = rp * W1[d] + b1[d];
  hv = (hv >= 0.f) ? hv : PRELU_A * hv;
  h[d] = hv;
  __syncthreads();
  if (r < 2*TT - 1) {
    float o = b2[d];
    for (int j = 0; j < 64; ++j) o += h[j] * W2[j*64 + d];
    rel[r*64 + d] = o;
  } else {
    rel[r*64 + d] = 0.f;
  }
}

// LN -> bf16; optionally dual-writes keyframe rows into hk[b*11+j] (fused
// gather for the K/V projection input).
__global__ __launch_bounds__(256)
void ln_bf16(const float* __restrict__ x, const float* __restrict__ g,
             const float* __restrict__ b, u16* __restrict__ out,
             u16* __restrict__ hk)
{
  const long row = blockIdx.x;
  const float4 v = ((const float4*)(x + row*1024))[threadIdx.x];
  float s  = v.x + v.y + v.z + v.w;
  float s2 = v.x*v.x + v.y*v.y + v.z*v.z + v.w*v.w;
  #pragma unroll
  for (int m = 32; m; m >>= 1) { s += __shfl_xor(s, m); s2 += __shfl_xor(s2, m); }
  __shared__ float red[8];
  const int wid = threadIdx.x >> 6;
  if ((threadIdx.x & 63) == 0) { red[wid] = s; red[wid+4] = s2; }
  __syncthreads();
  s  = red[0] + red[1] + red[2] + red[3];
  s2 = red[4] + red[5] + red[6] + red[7];
  const float mean = s * (1.f/1024.f);
  const float var  = fmaxf(s2 * (1.f/1024.f) - mean*mean, 0.f);
  const float rs   = rsqrtf(var + 1e-5f);
  const float4 gg = ((const float4*)g)[threadIdx.x];
  const float4 bb = ((const float4*)b)[threadIdx.x];
  ushort4 o;
  o.x = f2bf((v.x-mean)*rs*gg.x + bb.x);
  o.y = f2bf((v.y-mean)*rs*gg.y + bb.y);
  o.z = f2bf((v.z-mean)*rs*gg.z + bb.z);
  o.w = f2bf((v.w-mean)*rs*gg.w + bb.w);
  ((ushort4*)(out + row*1024))[threadIdx.x] = o;
  if (hk) {
    const int t = (int)(row % TT);
    if (t < 10 || t == TT-1) {
      const int bidx = (int)(row / TT);
      const int j = (t < 10) ? t : 10;
      ((ushort4*)(hk + (long)(bidx*11 + j)*1024))[threadIdx.x] = o;
    }
  }
}

// 11-key masked attention: one BLOCK (256 thr) per row. Thread t covers
// head n=t>>4, float4-slot dq=t&15 -> q/kv/rel/out reads all coalesced.
// Score reduce = 4 shfl_xor within the 16-lane head group. kv:[384,2048](K|V).
__global__ __launch_bounds__(256)
void attn11(const float* __restrict__ q, const float* __restrict__ kv,
            const float* __restrict__ rel, u16* __restrict__ o)
{
  const int row = blockIdx.x;
  const int b = row / TT, i = row - b*TT;
  const int t = threadIdx.x;
  const int n = t >> 4;         // head
  const int dq = t & 15;        // float4 slot within head
  const float4 qv = *(const float4*)(q + (long)row*1024 + t*4);
  float e[11];
  float mx = -1e30f;
  #pragma unroll
  for (int j = 0; j < 11; ++j) {
    const int kf = (j < 10) ? j : (TT-1);
    const float4 k4 = *(const float4*)(kv + (long)(b*11 + j)*2048 + n*64 + dq*4);
    const float4 r4 = *(const float4*)(rel + (kf - i + TT-1)*64 + dq*4);
    float s = qv.x*(k4.x+r4.x) + qv.y*(k4.y+r4.y)
            + qv.z*(k4.z+r4.z) + qv.w*(k4.w+r4.w);
    s += __shfl_xor(s, 1); s += __shfl_xor(s, 2);
    s += __shfl_xor(s, 4); s += __shfl_xor(s, 8);
    e[j] = s * 0.125f;           // 1/sqrt(64)
    mx = fmaxf(mx, e[j]);
  }
  float den = 0.f;
  #pragma unroll
  for (int j = 0; j < 11; ++j) { e[j] = __expf(e[j] - mx); den += e[j]; }
  const float inv = 1.f / den;
  float ax = 0.f, ay = 0.f, az = 0.f, aw = 0.f;
  #pragma unroll
  for (int j = 0; j < 11; ++j) {
    const float4 v4 = *(const float4*)(kv + (long)(b*11 + j)*2048 + 1024 + n*64 + dq*4);
    ax += e[j]*v4.x; ay += e[j]*v4.y; az += e[j]*v4.z; aw += e[j]*v4.w;
  }
  ushort4 ov;
  ov.x = f2bf(ax*inv); ov.y = f2bf(ay*inv); ov.z = f2bf(az*inv); ov.w = f2bf(aw*inv);
  *(ushort4*)(o + (long)row*1024 + t*4) = ov;
}

__global__ __launch_bounds__(256)
void kfadd(float* __restrict__ x, const float* __restrict__ kfe)
{
  const long idx = (long)blockIdx.x*256 + threadIdx.x;   // float4 index
  if (idx >= (long)NT*256) return;
  const int t = (int)((idx >> 8) % TT);
  const int c4 = (int)(idx & 255);
  float4 a = ((float4*)x)[idx];
  const float4 kk = ((const float4*)kfe)[t*256 + c4];
  a.x += kk.x; a.y += kk.y; a.z += kk.z; a.w += kk.w;
  ((float4*)x)[idx] = a;
}

__global__ __launch_bounds__(256)
void softmax8(const float* __restrict__ lg, float* __restrict__ gate)
{
  const int t = blockIdx.x*256 + threadIdx.x;
  if (t >= NT) return;
  float v[8], mx = -1e30f;
  #pragma unroll
  for (int e = 0; e < 8; ++e) { v[e] = lg[t*8 + e]; mx = fmaxf(mx, v[e]); }
  float den = 0.f;
  #pragma unroll
  for (int e = 0; e < 8; ++e) { v[e] = __expf(v[e] - mx); den += v[e]; }
  const float inv = 1.f / den;
  #pragma unroll
  for (int e = 0; e < 8; ++e) gate[t*8 + e] = v[e] * inv;
}

// ---------------- host ------------------------------------------------------
extern "C" void kernel_launch(void* const* d_in, const int* in_sizes, int n_in,
                              void* d_out, int out_size, void* d_ws, size_t ws_size,
                              hipStream_t stream)
{
  (void)in_sizes; (void)n_in; (void)out_size; (void)ws_size;
  const float* motion  = (const float*)d_in[0];
  const float* phase   = (const float*)d_in[1];
  const float* enc_W1  = (const float*)d_in[2];
  const float* enc_b1  = (const float*)d_in[3];
  const float* enc_W2  = (const float*)d_in[4];
  const float* enc_b2  = (const float*)d_in[5];
  const float* kf_W1   = (const float*)d_in[6];
  const float* kf_b1   = (const float*)d_in[7];
  const float* kf_W2   = (const float*)d_in[8];
  const float* kf_b2   = (const float*)d_in[9];
  const float* rp_W1   = (const float*)d_in[10];
  const float* rp_b1   = (const float*)d_in[11];
  const float* rp_W2   = (const float*)d_in[12];
  const float* rp_b2   = (const float*)d_in[13];
  const float* att_Wq  = (const float*)d_in[14];
  const float* att_bq  = (const float*)d_in[15];
  const float* att_Wk  = (const float*)d_in[16];
  const float* att_bk  = (const float*)d_in[17];
  const float* att_Wv  = (const float*)d_in[18];
  const float* att_bv  = (const float*)d_in[19];
  const float* att_Wo  = (const float*)d_in[20];
  const float* att_bo  = (const float*)d_in[21];
  const float* att_ln_g = (const float*)d_in[22];
  const float* att_ln_b = (const float*)d_in[23];
  const float* pff_W1  = (const float*)d_in[24];
  const float* pff_b1  = (const float*)d_in[25];
  const float* pff_W2  = (const float*)d_in[26];
  const float* pff_b2  = (const float*)d_in[27];
  const float* pff_ln_g = (const float*)d_in[28];
  const float* pff_ln_b = (const float*)d_in[29];
  const float* fin_ln_g = (const float*)d_in[30];
  const float* fin_ln_b = (const float*)d_in[31];
  const float* pd_W1   = (const float*)d_in[32];
  const float* pd_b1   = (const float*)d_in[33];
  const float* pd_W2   = (const float*)d_in[34];
  const float* pd_b2   = (const float*)d_in[35];
  const float* g_W1    = (const float*)d_in[36];
  const float* g_b1    = (const float*)d_in[37];
  const float* g_W2    = (const float*)d_in[38];
  const float* g_b2    = (const float*)d_in[39];
  const float* g_W3    = (const float*)d_in[40];
  const float* g_b3    = (const float*)d_in[41];
  const float* md_W0   = (const float*)d_in[42];
  const float* md_b0   = (const float*)d_in[43];
  const float* md_W1   = (const float*)d_in[44];
  const float* md_b1   = (const float*)d_in[45];
  const float* md_W2   = (const float*)d_in[46];
  const float* md_b2   = (const float*)d_in[47];

  char* wsp = (char*)d_ws;
  size_t off = 0;
  auto alloc = [&](size_t bytes) -> char* {
    char* p = wsp + off;
    off += (bytes + 255) & ~(size_t)255;
    return p;
  };

  // bf16 transposed weights [Npad, Kpad]
  u16* encW1T = (u16*)alloc((size_t)1024*320*2);
  u16* encW2T = (u16*)alloc((size_t)1024*1024*2);
  u16* kfW1T  = (u16*)alloc((size_t)1024*64*2);
  u16* kfW2T  = (u16*)alloc((size_t)1024*1024*2);
  u16* WqT    = (u16*)alloc((size_t)8*1024*1024*2);
  u16* kvT    = (u16*)alloc((size_t)8*2048*1024*2);   // per layer: [Wk^T ; Wv^T]
  u16* WoT    = (u16*)alloc((size_t)8*1024*1024*2);
  u16* F1T    = (u16*)alloc((size_t)8*4096*1024*2);
  u16* F2T    = (u16*)alloc((size_t)8*1024*4096*2);
  u16* pdW1T  = (u16*)alloc((size_t)1024*1024*2);
  u16* pdW2T  = (u16*)alloc((size_t)128*1024*2);
  u16* gW1T   = (u16*)alloc((size_t)512*64*2);
  u16* gW2T   = (u16*)alloc((size_t)512*512*2);
  u16* gW3T   = (u16*)alloc((size_t)128*512*2);
  u16* md0T   = (u16*)alloc((size_t)8*1024*1024*2);   // [8192,1024] rows=e*1024+n
  u16* md1T   = (u16*)alloc((size_t)8*1024*1024*2);
  u16* md2T   = (u16*)alloc((size_t)8*256*1024*2);    // [2048,1024]

  // activations
  float* x    = (float*)alloc((size_t)NT*1024*4);   // residual stream
  float* rel  = (float*)alloc((size_t)384*64*4);
  u16*   kp   = (u16*)  alloc((size_t)256*64*2);
  u16*   kf1  = (u16*)  alloc((size_t)256*1024*2);
  float* kfe  = (float*)alloc((size_t)256*1024*4);
  u16*   hk   = (u16*)  alloc((size_t)384*1024*2);
  float* kvb  = (float*)alloc((size_t)8*2048*4);    // concat K/V bias
  float* kvbuf= (float*)alloc((size_t)384*2048*4);
  u16*   phbf = (u16*)  alloc((size_t)NT*64*2);
  float* glog = (float*)alloc((size_t)NT*8*4);
  float* gate = (float*)alloc((size_t)NT*8*4);
  u16*   xin  = (u16*)  alloc((size_t)NT*320*2);
  u16*   s1   = (u16*)  alloc((size_t)NT*1024*2);   // h_bf / xf_bf / y1_bf
  float* s2   = (float*)alloc((size_t)NT*1024*4);   // q f32
  u16*   s3   = (u16*)  alloc((size_t)NT*1024*2);   // o_bf / pd1 / gh1 / y0_bf
  u16*   s4   = (u16*)  alloc((size_t)NT*4096*2);   // f1_bf / gh2 / MoE C half 0
  u16*   s5   = (u16*)  alloc((size_t)NT*4096*2);   // MoE C half 1

  float* outY = (float*)d_out;              // [NT,256]
  float* outP = outY + (size_t)NT*256;      // [NT,16]

  auto tr = [&](const float* s_, u16* d_, int K, int N, int Kp, int Np, int batch,
                long dstride) {
    dim3 g((Np+63)/64, (Kp+63)/64, batch);
    transpose_bf16<<<g, 256, 0, stream>>>(s_, d_, K, N, Kp, Np, (long)K*N, dstride);
  };
  auto g64 = [&](const u16* A, const u16* Bt, const float* bias, int biasN,
                 float* Cf, int ldc, int Nf, int accum,
                 u16* Cb, int ldcb, int Nb, int M, int K, int Npad, int act) {
    gemm64<<<dim3(M/64, Npad/128), 256, 0, stream>>>(
        A, Bt, bias, biasN, Cf, ldc, Nf, accum, Cb, ldcb, Nb, K, act);
  };
  auto g128 = [&](const u16* A, const u16* Bt, const float* bias, int biasN,
                  float* Cf, int ldc, int Nf, int accum,
                  u16* Cb, int ldcb, int Nb, int M, int K, int Npad, int act) {
    gemm128<<<dim3(M/128, Npad/128), 256, 0, stream>>>(
        A, Bt, bias, biasN, Cf, ldc, Nf, accum, Cb, ldcb, Nb, K, act);
  };

  // ---- weight conversion/transposition (every launch; deterministic) ----
  tr(enc_W1, encW1T, 273, 1024, 320, 1024, 1, (long)1024*320);
  tr(enc_W2, encW2T, 1024, 1024, 1024, 1024, 1, (long)1024*1024);
  tr(kf_W1,  kfW1T,  2, 1024, 64, 1024, 1, (long)1024*64);
  tr(kf_W2,  kfW2T,  1024, 1024, 1024, 1024, 1, (long)1024*1024);
  tr(att_Wq, WqT, 1024, 1024, 1024, 1024, 8, (long)1024*1024);
  tr(att_Wk, kvT,               1024, 1024, 1024, 1024, 8, (long)2048*1024);
  tr(att_Wv, kvT + (size_t)1024*1024, 1024, 1024, 1024, 1024, 8, (long)2048*1024);
  tr(att_Wo, WoT, 1024, 1024, 1024, 1024, 8, (long)1024*1024);
  tr(pff_W1, F1T, 1024, 4096, 1024, 4096, 8, (long)4096*1024);
  tr(pff_W2, F2T, 4096, 1024, 4096, 1024, 8, (long)1024*4096);
  tr(pd_W1,  pdW1T, 1024, 1024, 1024, 1024, 1, (long)1024*1024);
  tr(pd_W2,  pdW2T, 1024, 16, 1024, 128, 1, (long)128*1024);
  tr(g_W1,   gW1T, 16, 512, 64, 512, 1, (long)512*64);
  tr(g_W2,   gW2T, 512, 512, 512, 512, 1, (long)512*512);
  tr(g_W3,   gW3T, 512, 8, 512, 128, 1, (long)128*512);
  tr(md_W0,  md0T, 1024, 1024, 1024, 1024, 8, (long)1024*1024);
  tr(md_W1,  md1T, 1024, 1024, 1024, 1024, 8, (long)1024*1024);
  tr(md_W2,  md2T, 1024, 256, 1024, 256, 8, (long)256*1024);

  // ---- small precompute ----
  build_xin<<<(NT*320 + 255)/256, 256, 0, stream>>>(motion, phase, xin);
  build_kp<<<(256*64 + 255)/256, 256, 0, stream>>>(kp);
  cat_kv_bias<<<(8*2048 + 255)/256, 256, 0, stream>>>(att_bk, att_bv, kvb);
  relpos<<<384, 64, 0, stream>>>(rp_W1, rp_b1, rp_W2, rp_b2, rel);

  // ---- encoder ----
  g64(xin, encW1T, enc_b1, 1024, nullptr,0,0,0, s1,1024,1024, NT, 320, 1024, 2);
  g64(s1,  encW2T, enc_b2, 1024, x,1024,1024,0, nullptr,0,0, NT, 1024, 1024, 2);
  // ---- keyframe embedding ----
  g64(kp,  kfW1T, kf_b1, 1024, nullptr,0,0,0, kf1,1024,1024, 256, 64, 1024, 2);
  g64(kf1, kfW2T, kf_b2, 1024, kfe,1024,1024,0, nullptr,0,0, 256, 1024, 1024, 0);
  kfadd<<<NT, 256, 0, stream>>>(x, kfe);

  // ---- transformer layers ----
  for (int l = 0; l < 8; ++l) {
    const size_t w1 = (size_t)l*1024*1024;
    const size_t wf = (size_t)l*4096*1024;
    ln_bf16<<<NT, 256, 0, stream>>>(x, att_ln_g + l*1024, att_ln_b + l*1024, s1, hk);
    g64(s1, WqT + w1, att_bq + l*1024, 1024, s2,1024,1024,0, nullptr,0,0, NT, 1024, 1024, 0);
    g64(hk, kvT + (size_t)l*2048*1024, kvb + l*2048, 2048,
        kvbuf,2048,2048,0, nullptr,0,0, 384, 1024, 2048, 0);
    attn11<<<NT, 256, 0, stream>>>(s2, kvbuf, rel, s3);
    g64(s3, WoT + w1, att_bo + l*1024, 1024, x,1024,1024,1, nullptr,0,0, NT, 1024, 1024, 0);
    ln_bf16<<<NT, 256, 0, stream>>>(x, pff_ln_g + l*1024, pff_ln_b + l*1024, s1, nullptr);
    g128(s1, F1T + wf, pff_b1 + l*4096, 4096, nullptr,0,0,0, s4,4096,4096, NT, 1024, 4096, 1);
    g64(s4, F2T + wf, pff_b2 + l*1024, 1024, x,1024,1024,1, nullptr,0,0, NT, 4096, 1024, 0);
  }

  // ---- final LN + phase decoder ----
  ln_bf16<<<NT, 256, 0, stream>>>(x, fin_ln_g, fin_ln_b, s1, nullptr);   // xf_bf
  g64(s1, pdW1T, pd_b1, 1024, nullptr,0,0,0, s3,1024,1024, NT, 1024, 1024, 2);
  g64(s3, pdW2T, pd_b2, 16, outP,16,16,0, phbf,64,64, NT, 1024, 128, 0);

  // ---- gating ----
  g64(phbf, gW1T, g_b1, 512, nullptr,0,0,0, s3,512,512, NT, 64, 512, 2);
  g64(s3,   gW2T, g_b2, 512, nullptr,0,0,0, s4,512,512, NT, 512, 512, 2);
  g64(s4,   gW3T, g_b3, 8,  glog,8,8,0, nullptr,0,0, NT, 512, 128, 0);
  softmax8<<<(NT + 255)/256, 256, 0, stream>>>(glog, gate);

  // ---- mixture-of-experts decoder (experts concatenated along N) ----
  const int BL2 = (int)(((long)NT*256 + 255)/256);
  // level 0: x(s1) -> y0(s3)
  g128(s1, md0T,                     md_b0,        4096, nullptr,0,0,0, s4,4096,4096, NT, 1024, 4096, 0);
  g128(s1, md0T + (size_t)4096*1024, md_b0 + 4096, 4096, nullptr,0,0,0, s5,4096,4096, NT, 1024, 4096, 0);
  moe_blend2<<<BL2, 256, 0, stream>>>(s4, s5, gate, s3);
  // level 1: y0(s3) -> y1(s1)
  g128(s3, md1T,                     md_b1,        4096, nullptr,0,0,0, s4,4096,4096, NT, 1024, 4096, 0);
  g128(s3, md1T + (size_t)4096*1024, md_b1 + 4096, 4096, nullptr,0,0,0, s5,4096,4096, NT, 1024, 4096, 0);
  moe_blend2<<<BL2, 256, 0, stream>>>(s4, s5, gate, s1);
  // level 2: y1(s1) -> outY
  g128(s1, md2T, md_b2, 2048, nullptr,0,0,0, s4,2048,2048, NT, 1024, 2048, 0);
  moe_blend_out<<<(int)(((long)NT*64 + 255)/256), 256, 0, stream>>>(s4, gate, outY);
}

// Round 15
// 3002.805 us; speedup vs baseline: 1.0306x; 1.0306x over previous
//
#include <hip/hip_runtime.h>
#include <stdint.h>

typedef unsigned short u16;
typedef __attribute__((ext_vector_type(4))) float f32x4;
typedef __attribute__((ext_vector_type(8))) __bf16 bf16x8;

#define NT 6144     // B*T
#define TT 192
#define PRELU_A 0.25f

__device__ __forceinline__ u16 f2bf(float f) {
  unsigned u = __float_as_uint(f);
  u += 0x7fffu + ((u >> 16) & 1u);
  return (u16)(u >> 16);
}
__device__ __forceinline__ float bf2f(u16 u) {
  return __uint_as_float(((unsigned)u) << 16);
}

__device__ __forceinline__ void gload16(const u16* g, __bf16* l) {
  auto* l3 = reinterpret_cast<__attribute__((address_space(3))) __bf16*>(
      reinterpret_cast<uintptr_t>(l));
  const auto* g1 = reinterpret_cast<const __attribute__((address_space(1))) u16*>(
      reinterpret_cast<uintptr_t>(g));
  __builtin_amdgcn_global_load_lds(g1, l3, 16, 0, 0);
}

// XCD-contiguous (m204 bijective) + supertile decode (R14-verified).
__device__ __forceinline__ void xcd_remap(int& bx, int& by)
{
  const int gx = gridDim.x, gy = gridDim.y;
  const int nwg = gx * gy;
  const int f = blockIdx.y * gx + blockIdx.x;
  const int q = nwg >> 3, r = nwg & 7;
  const int xcd = f & 7, s = f >> 3;
  const int w = (xcd < r ? xcd*(q+1) : r*(q+1) + (xcd-r)*q) + s;
  const int CX = ((gx & 7) == 0) ? (gx >> 3) : 1;
  const int per = gy * CX;
  const int c = w / per, rr = w - c*per;
  bx = c*CX + (rr % CX);
  by = rr / CX;
}

// ---------------- merged transpose: all weights in ONE dispatch --------------
struct TrDesc {
  const float* src; u16* dst;
  int K, N, Kp, Np;
  int tilesX, perBatch, batch, tileOff;
  long sstride, dstride;
};
struct TrTable { TrDesc d[18]; int n; };

__global__ __launch_bounds__(256)
void transpose_all(TrTable T)
{
  __shared__ float tile[64][65];
  const int bid = blockIdx.x;
  TrDesc de;
  #pragma unroll 1
  for (int i = 0; i < T.n; ++i) {
    const TrDesc& e = T.d[i];
    if (bid >= e.tileOff && bid < e.tileOff + e.perBatch * e.batch) { de = e; break; }
  }
  const int local = bid - de.tileOff;
  const int z = local / de.perBatch;
  const int rem = local - z * de.perBatch;
  const int ty = rem / de.tilesX;
  const int tx = rem - ty * de.tilesX;
  const float* src = de.src + (long)z * de.sstride;
  u16* dst = de.dst + (long)z * de.dstride;
  const int kt = ty * 64, nt2 = tx * 64;
  #pragma unroll
  for (int i = 0; i < 16; ++i) {
    int idx = threadIdx.x + i*256;
    int kl = idx >> 6, nl = idx & 63;
    int k = kt + kl, n = nt2 + nl;
    tile[kl][nl] = (k < de.K && n < de.N) ? src[(long)k*de.N + n] : 0.f;
  }
  __syncthreads();
  #pragma unroll
  for (int i = 0; i < 16; ++i) {
    int idx = threadIdx.x + i*256;
    int nl = idx >> 6, kl = idx & 63;
    int n = nt2 + nl, k = kt + kl;
    if (n < de.Np && k < de.Kp) dst[(long)n*de.Kp + k] = f2bf(tile[kl][nl]);
  }
}

// ---------------- shared epilogue (COMPILE-TIME MR/HM — rule #20) ------------
// radd: optional row-broadcast add (v += radd[(grow%TT)*1024 + gcol]) AFTER act.
template<int MR, int HM>
__device__ __forceinline__ void epilogue_store(
    f32x4 (&acc)[MR][4], long arow0, long brow0, int wm, int wn, int lane,
    const float* bias, int biasN,
    float* Cf, int ldc, int Nf, int accum,
    u16* Cb, int ldcb, int Nb, int act, const float* radd)
{
  const int rbase = wm*HM + ((lane >> 4) << 2);
  const int cbase = wn*64 + (lane & 15);
  #pragma unroll
  for (int m = 0; m < MR; ++m) {
    #pragma unroll
    for (int n = 0; n < 4; ++n) {
      const long gcol = brow0 + cbase + n*16;
      const float bv = (bias && gcol < biasN) ? bias[gcol] : 0.f;
      #pragma unroll
      for (int r = 0; r < 4; ++r) {
        const long grow = arow0 + rbase + m*16 + r;
        float v = acc[m][n][r] + bv;
        if (act == 1) v = fmaxf(v, 0.f);
        else if (act == 2) v = (v >= 0.f) ? v : PRELU_A * v;
        if (radd) v += radd[(int)(grow % TT)*1024 + gcol];
        if (Cf && gcol < Nf) {
          const long idx = grow * (long)ldc + gcol;
          Cf[idx] = accum ? (Cf[idx] + v) : v;
        }
        if (Cb && gcol < Nb) Cb[grow * (long)ldcb + gcol] = f2bf(v);
      }
    }
  }
}

// ---------------- 64x128 bf16 GEMM, BK=64, ring-2 counted-vmcnt (R9/R11) -----
__global__ __launch_bounds__(256, 3)
void gemm64(const u16* __restrict__ A, const u16* __restrict__ Bt,
            const float* __restrict__ bias, int biasN,
            float* __restrict__ Cf, int ldc, int Nf, int accum,
            u16* __restrict__ Cb, int ldcb, int Nb,
            int K, int act, const float* __restrict__ radd)
{
  __shared__ __bf16 As[2*64*64];
  __shared__ __bf16 Bs[2*128*64];
  const int tid = threadIdx.x;
  const int wid = tid >> 6;
  const int lane = tid & 63;
  const int wm = wid >> 1, wn = wid & 1;
  int bx, by; xcd_remap(bx, by);
  const long arow0 = (long)bx * 64;
  const long brow0 = (long)by * 128;
  const int lr  = lane >> 3;
  const int lko = ((lane & 7) ^ (lane >> 3)) << 3;

  f32x4 acc[2][4];
  #pragma unroll
  for (int m = 0; m < 2; ++m)
    #pragma unroll
    for (int n = 0; n < 4; ++n) acc[m][n] = (f32x4)0.f;

  const int aro = lane & 15;
  const int g = lane >> 4;

  auto stage = [&](int buf, int kt) {
    #pragma unroll
    for (int c = wid; c < 24; c += 4) {
      if (c < 8) gload16(A + (arow0 + c*8 + lr)*K + kt + lko, As + buf*(64*64) + c*512);
      else       gload16(Bt + (brow0 + (c-8)*8 + lr)*K + kt + lko,
                         Bs + buf*(128*64) + (c-8)*512);
    }
  };

  const int nt = K >> 6;
  stage(0, 0);
  for (int t = 0; t < nt; ++t) {
    if (t + 1 < nt) {
      stage((t+1) & 1, (t+1) << 6);
      asm volatile("s_waitcnt vmcnt(6)" ::: "memory");
    } else {
      asm volatile("s_waitcnt vmcnt(0)" ::: "memory");
    }
    __builtin_amdgcn_s_barrier();
    asm volatile("" ::: "memory");
    const __bf16* Ab = As + (t&1)*(64*64);
    const __bf16* Bb = Bs + (t&1)*(128*64);
    #pragma unroll
    for (int kk = 0; kk < 2; ++kk) {
      bf16x8 af[2], bfv[4];
      #pragma unroll
      for (int m = 0; m < 2; ++m) {
        const int R = wm*32 + m*16 + aro;
        af[m] = *(const bf16x8*)(Ab + R*64 + (((kk*4 + g) ^ (R & 7)) << 3));
      }
      #pragma unroll
      for (int n = 0; n < 4; ++n) {
        const int R = wn*64 + n*16 + aro;
        bfv[n] = *(const bf16x8*)(Bb + R*64 + (((kk*4 + g) ^ (R & 7)) << 3));
      }
      #pragma unroll
      for (int m = 0; m < 2; ++m)
        #pragma unroll
        for (int n = 0; n < 4; ++n)
          acc[m][n] = __builtin_amdgcn_mfma_f32_16x16x32_bf16(af[m], bfv[n], acc[m][n], 0, 0, 0);
    }
    asm volatile("" ::: "memory");
    __builtin_amdgcn_s_barrier();    // readers done before next stage overwrites
  }
  epilogue_store<2,32>(acc, arow0, brow0, wm, wn, lane,
                       bias, biasN, Cf, ldc, Nf, accum, Cb, ldcb, Nb, act, radd);
}

// ---------------- 128x128 bf16 GEMM, BK=32, ring-2, 32KB LDS (R13) -----------
__global__ __launch_bounds__(256, 4)
void gemm128(const u16* __restrict__ A, const u16* __restrict__ Bt,
             const float* __restrict__ bias, int biasN,
             float* __restrict__ Cf, int ldc, int Nf, int accum,
             u16* __restrict__ Cb, int ldcb, int Nb,
             int K, int act)
{
  __shared__ __bf16 As[2*128*32];
  __shared__ __bf16 Bs[2*128*32];
  const int tid = threadIdx.x;
  const int wid = tid >> 6;
  const int lane = tid & 63;
  const int wm = wid >> 1, wn = wid & 1;
  int bx, by; xcd_remap(bx, by);
  const long arow0 = (long)bx * 128;
  const long brow0 = (long)by * 128;
  const int srow = lane >> 2;
  const int skoff = ((lane & 3) ^ ((lane >> 3) & 3)) << 3;

  f32x4 acc[4][4];
  #pragma unroll
  for (int m = 0; m < 4; ++m)
    #pragma unroll
    for (int n = 0; n < 4; ++n) acc[m][n] = (f32x4)0.f;

  const int aro = lane & 15;
  const int g = lane >> 4;

  auto stage = [&](int buf, int kt) {
    #pragma unroll
    for (int c = wid; c < 16; c += 4) {
      if (c < 8) gload16(A + (arow0 + c*16 + srow)*K + kt + skoff, As + buf*4096 + c*512);
      else       gload16(Bt + (brow0 + (c-8)*16 + srow)*K + kt + skoff,
                         Bs + buf*4096 + (c-8)*512);
    }
  };

  const int nt = K >> 5;
  stage(0, 0);
  for (int t = 0; t < nt; ++t) {
    if (t + 1 < nt) {
      stage((t+1) & 1, (t+1) << 5);
      asm volatile("s_waitcnt vmcnt(4)" ::: "memory");
    } else {
      asm volatile("s_waitcnt vmcnt(0)" ::: "memory");
    }
    __builtin_amdgcn_s_barrier();
    asm volatile("" ::: "memory");
    const __bf16* Ab = As + (t&1)*4096;
    const __bf16* Bb = Bs + (t&1)*4096;
    bf16x8 af[4], bfv[4];
    #pragma unroll
    for (int m = 0; m < 4; ++m) {
      const int R = wm*64 + m*16 + aro;
      af[m] = *(const bf16x8*)(Ab + R*32 + ((g ^ ((R >> 1) & 3)) << 3));
    }
    #pragma unroll
    for (int n = 0; n < 4; ++n) {
      const int R = wn*64 + n*16 + aro;
      bfv[n] = *(const bf16x8*)(Bb + R*32 + ((g ^ ((R >> 1) & 3)) << 3));
    }
    #pragma unroll
    for (int m = 0; m < 4; ++m)
      #pragma unroll
      for (int n = 0; n < 4; ++n)
        acc[m][n] = __builtin_amdgcn_mfma_f32_16x16x32_bf16(af[m], bfv[n], acc[m][n], 0, 0, 0);
    asm volatile("" ::: "memory");
    __builtin_amdgcn_s_barrier();    // readers done before next stage overwrites
  }
  epilogue_store<4,64>(acc, arow0, brow0, wm, wn, lane,
                       bias, biasN, Cf, ldc, Nf, accum, Cb, ldcb, Nb, act, nullptr);
}

// --- MoE blend (2 half-buffers, H=1024): out = prelu(sum_e gate_e * C_e) ----
__global__ __launch_bounds__(256)
void moe_blend2(const u16* __restrict__ C0, const u16* __restrict__ C1,
                const float* __restrict__ gate, u16* __restrict__ outb)
{
  const long idx = (long)blockIdx.x*256 + threadIdx.x;   // float4 over [NT,1024]
  if (idx >= (long)NT*256) return;
  const long t = idx >> 8;
  const int h = (int)(idx & 255) << 2;
  float sx = 0.f, sy = 0.f, sz = 0.f, sw = 0.f;
  #pragma unroll
  for (int j = 0; j < 4; ++j) {
    const float gv = gate[t*8 + j];
    const ushort4 c4 = *(const ushort4*)(C0 + t*4096 + j*1024 + h);
    sx += gv * bf2f(c4.x); sy += gv * bf2f(c4.y);
    sz += gv * bf2f(c4.z); sw += gv * bf2f(c4.w);
  }
  #pragma unroll
  for (int j = 0; j < 4; ++j) {
    const float gv = gate[t*8 + 4 + j];
    const ushort4 c4 = *(const ushort4*)(C1 + t*4096 + j*1024 + h);
    sx += gv * bf2f(c4.x); sy += gv * bf2f(c4.y);
    sz += gv * bf2f(c4.z); sw += gv * bf2f(c4.w);
  }
  sx = (sx >= 0.f) ? sx : PRELU_A * sx;
  sy = (sy >= 0.f) ? sy : PRELU_A * sy;
  sz = (sz >= 0.f) ? sz : PRELU_A * sz;
  sw = (sw >= 0.f) ? sw : PRELU_A * sw;
  ushort4 o; o.x = f2bf(sx); o.y = f2bf(sy); o.z = f2bf(sz); o.w = f2bf(sw);
  *(ushort4*)(outb + t*1024 + h) = o;
}

// --- MoE final blend (level 2, H=256, 8 experts contiguous) -> f32 out -------
__global__ __launch_bounds__(256)
void moe_blend_out(const u16* __restrict__ C, const float* __restrict__ gate,
                   float* __restrict__ outf)
{
  const long idx = (long)blockIdx.x*256 + threadIdx.x;   // float4 over [NT,256]
  if (idx >= (long)NT*64) return;
  const long t = idx >> 6;
  const int h = (int)(idx & 63) << 2;
  float sx = 0.f, sy = 0.f, sz = 0.f, sw = 0.f;
  #pragma unroll
  for (int j = 0; j < 8; ++j) {
    const float gv = gate[t*8 + j];
    const ushort4 c4 = *(const ushort4*)(C + t*2048 + j*256 + h);
    sx += gv * bf2f(c4.x); sy += gv * bf2f(c4.y);
    sz += gv * bf2f(c4.z); sw += gv * bf2f(c4.w);
  }
  float4 o; o.x = sx; o.y = sy; o.z = sz; o.w = sw;
  ((float4*)(outf + t*256))[h >> 2] = o;
}

// ---------------- small helper kernels --------------------------------------
__global__ __launch_bounds__(256)
void build_xin(const float* __restrict__ motion, const float* __restrict__ phase,
               u16* __restrict__ xin)   // [NT, 320] zero-padded
{
  const long idx = (long)blockIdx.x*256 + threadIdx.x;
  if (idx >= (long)NT*320) return;
  const int c = (int)(idx % 320);
  const long row = idx / 320;
  const int t = (int)(row % TT);
  const bool dm = (t < 10) || (t == TT-1);
  float v;
  if (c < 256)       v = dm ? motion[row*256 + c] : 0.f;
  else if (c == 256) v = dm ? 1.f : 0.f;
  else if (c < 273)  v = dm ? phase[row*16 + (c-257)] : 0.f;
  else               v = 0.f;
  xin[idx] = f2bf(v);
}

// kp [256,64] zero-padded + concat K/V bias [8][2048] in one launch
__global__ __launch_bounds__(256)
void build_kp_kvb(u16* __restrict__ kp,
                  const float* __restrict__ bk, const float* __restrict__ bv,
                  float* __restrict__ kvb)
{
  const int idx = blockIdx.x*256 + threadIdx.x;
  if (idx < 256*64) {
    const int r = idx / 64, c = idx % 64;
    float v = 0.f;
    if (r < TT) {
      if (c == 0) v = (float)(r - 9);
      else if (c == 1) v = (float)(TT-1 - r);
    }
    kp[idx] = f2bf(v);
  } else {
    const int j = idx - 256*64;
    if (j < 8*2048) {
      const int l = j >> 11, c = j & 2047;
      kvb[j] = (c < 1024) ? bk[l*1024 + c] : bv[l*1024 + c - 1024];
    }
  }
}

__global__ __launch_bounds__(64)
void relpos(const float* __restrict__ W1, const float* __restrict__ b1,
            const float* __restrict__ W2, const float* __restrict__ b2,
            float* __restrict__ rel)
{
  const int r = blockIdx.x;      // 0..383 (rows >=383 zeroed, never read)
  const int d = threadIdx.x;
  __shared__ float h[64];
  const float rp = (float)(r - (TT-1));
  float hv = rp * W1[d] + b1[d];
  hv = (hv >= 0.f) ? hv : PRELU_A * hv;
  h[d] = hv;
  __syncthreads();
  if (r < 2*TT - 1) {
    float o = b2[d];
    for (int j = 0; j < 64; ++j) o += h[j] * W2[j*64 + d];
    rel[r*64 + d] = o;
  } else {
    rel[r*64 + d] = 0.f;
  }
}

// LN -> bf16; optionally dual-writes keyframe rows into hk[b*11+j].
__global__ __launch_bounds__(256)
void ln_bf16(const float* __restrict__ x, const float* __restrict__ g,
             const float* __restrict__ b, u16* __restrict__ out,
             u16* __restrict__ hk)
{
  const long row = blockIdx.x;
  const float4 v = ((const float4*)(x + row*1024))[threadIdx.x];
  float s  = v.x + v.y + v.z + v.w;
  float s2 = v.x*v.x + v.y*v.y + v.z*v.z + v.w*v.w;
  #pragma unroll
  for (int m = 32; m; m >>= 1) { s += __shfl_xor(s, m); s2 += __shfl_xor(s2, m); }
  __shared__ float red[8];
  const int wid = threadIdx.x >> 6;
  if ((threadIdx.x & 63) == 0) { red[wid] = s; red[wid+4] = s2; }
  __syncthreads();
  s  = red[0] + red[1] + red[2] + red[3];
  s2 = red[4] + red[5] + red[6] + red[7];
  const float mean = s * (1.f/1024.f);
  const float var  = fmaxf(s2 * (1.f/1024.f) - mean*mean, 0.f);
  const float rs   = rsqrtf(var + 1e-5f);
  const float4 gg = ((const float4*)g)[threadIdx.x];
  const float4 bb = ((const float4*)b)[threadIdx.x];
  ushort4 o;
  o.x = f2bf((v.x-mean)*rs*gg.x + bb.x);
  o.y = f2bf((v.y-mean)*rs*gg.y + bb.y);
  o.z = f2bf((v.z-mean)*rs*gg.z + bb.z);
  o.w = f2bf((v.w-mean)*rs*gg.w + bb.w);
  ((ushort4*)(out + row*1024))[threadIdx.x] = o;
  if (hk) {
    const int t = (int)(row % TT);
    if (t < 10 || t == TT-1) {
      const int bidx = (int)(row / TT);
      const int j = (t < 10) ? t : 10;
      ((ushort4*)(hk + (long)(bidx*11 + j)*1024))[threadIdx.x] = o;
    }
  }
}

// 11-key masked attention: one BLOCK (256 thr) per row (R9-verified).
__global__ __launch_bounds__(256)
void attn11(const float* __restrict__ q, const float* __restrict__ kv,
            const float* __restrict__ rel, u16* __restrict__ o)
{
  const int row = blockIdx.x;
  const int b = row / TT, i = row - b*TT;
  const int t = threadIdx.x;
  const int n = t >> 4;         // head
  const int dq = t & 15;        // float4 slot within head
  const float4 qv = *(const float4*)(q + (long)row*1024 + t*4);
  float e[11];
  float mx = -1e30f;
  #pragma unroll
  for (int j = 0; j < 11; ++j) {
    const int kf = (j < 10) ? j : (TT-1);
    const float4 k4 = *(const float4*)(kv + (long)(b*11 + j)*2048 + n*64 + dq*4);
    const float4 r4 = *(const float4*)(rel + (kf - i + TT-1)*64 + dq*4);
    float s = qv.x*(k4.x+r4.x) + qv.y*(k4.y+r4.y)
            + qv.z*(k4.z+r4.z) + qv.w*(k4.w+r4.w);
    s += __shfl_xor(s, 1); s += __shfl_xor(s, 2);
    s += __shfl_xor(s, 4); s += __shfl_xor(s, 8);
    e[j] = s * 0.125f;           // 1/sqrt(64)
    mx = fmaxf(mx, e[j]);
  }
  float den = 0.f;
  #pragma unroll
  for (int j = 0; j < 11; ++j) { e[j] = __expf(e[j] - mx); den += e[j]; }
  const float inv = 1.f / den;
  float ax = 0.f, ay = 0.f, az = 0.f, aw = 0.f;
  #pragma unroll
  for (int j = 0; j < 11; ++j) {
    const float4 v4 = *(const float4*)(kv + (long)(b*11 + j)*2048 + 1024 + n*64 + dq*4);
    ax += e[j]*v4.x; ay += e[j]*v4.y; az += e[j]*v4.z; aw += e[j]*v4.w;
  }
  ushort4 ov;
  ov.x = f2bf(ax*inv); ov.y = f2bf(ay*inv); ov.z = f2bf(az*inv); ov.w = f2bf(aw*inv);
  *(ushort4*)(o + (long)row*1024 + t*4) = ov;
}

__global__ __launch_bounds__(256)
void softmax8(const float* __restrict__ lg, float* __restrict__ gate)
{
  const int t = blockIdx.x*256 + threadIdx.x;
  if (t >= NT) return;
  float v[8], mx = -1e30f;
  #pragma unroll
  for (int e = 0; e < 8; ++e) { v[e] = lg[t*8 + e]; mx = fmaxf(mx, v[e]); }
  float den = 0.f;
  #pragma unroll
  for (int e = 0; e < 8; ++e) { v[e] = __expf(v[e] - mx); den += v[e]; }
  const float inv = 1.f / den;
  #pragma unroll
  for (int e = 0; e < 8; ++e) gate[t*8 + e] = v[e] * inv;
}

// ---------------- host ------------------------------------------------------
extern "C" void kernel_launch(void* const* d_in, const int* in_sizes, int n_in,
                              void* d_out, int out_size, void* d_ws, size_t ws_size,
                              hipStream_t stream)
{
  (void)in_sizes; (void)n_in; (void)out_size; (void)ws_size;
  const float* motion  = (const float*)d_in[0];
  const float* phase   = (const float*)d_in[1];
  const float* enc_W1  = (const float*)d_in[2];
  const float* enc_b1  = (const float*)d_in[3];
  const float* enc_W2  = (const float*)d_in[4];
  const float* enc_b2  = (const float*)d_in[5];
  const float* kf_W1   = (const float*)d_in[6];
  const float* kf_b1   = (const float*)d_in[7];
  const float* kf_W2   = (const float*)d_in[8];
  const float* kf_b2   = (const float*)d_in[9];
  const float* rp_W1   = (const float*)d_in[10];
  const float* rp_b1   = (const float*)d_in[11];
  const float* rp_W2   = (const float*)d_in[12];
  const float* rp_b2   = (const float*)d_in[13];
  const float* att_Wq  = (const float*)d_in[14];
  const float* att_bq  = (const float*)d_in[15];
  const float* att_Wk  = (const float*)d_in[16];
  const float* att_bk  = (const float*)d_in[17];
  const float* att_Wv  = (const float*)d_in[18];
  const float* att_bv  = (const float*)d_in[19];
  const float* att_Wo  = (const float*)d_in[20];
  const float* att_bo  = (const float*)d_in[21];
  const float* att_ln_g = (const float*)d_in[22];
  const float* att_ln_b = (const float*)d_in[23];
  const float* pff_W1  = (const float*)d_in[24];
  const float* pff_b1  = (const float*)d_in[25];
  const float* pff_W2  = (const float*)d_in[26];
  const float* pff_b2  = (const float*)d_in[27];
  const float* pff_ln_g = (const float*)d_in[28];
  const float* pff_ln_b = (const float*)d_in[29];
  const float* fin_ln_g = (const float*)d_in[30];
  const float* fin_ln_b = (const float*)d_in[31];
  const float* pd_W1   = (const float*)d_in[32];
  const float* pd_b1   = (const float*)d_in[33];
  const float* pd_W2   = (const float*)d_in[34];
  const float* pd_b2   = (const float*)d_in[35];
  const float* g_W1    = (const float*)d_in[36];
  const float* g_b1    = (const float*)d_in[37];
  const float* g_W2    = (const float*)d_in[38];
  const float* g_b2    = (const float*)d_in[39];
  const float* g_W3    = (const float*)d_in[40];
  const float* g_b3    = (const float*)d_in[41];
  const float* md_W0   = (const float*)d_in[42];
  const float* md_b0   = (const float*)d_in[43];
  const float* md_W1   = (const float*)d_in[44];
  const float* md_b1   = (const float*)d_in[45];
  const float* md_W2   = (const float*)d_in[46];
  const float* md_b2   = (const float*)d_in[47];

  char* wsp = (char*)d_ws;
  size_t off = 0;
  auto alloc = [&](size_t bytes) -> char* {
    char* p = wsp + off;
    off += (bytes + 255) & ~(size_t)255;
    return p;
  };

  // bf16 transposed weights [Npad, Kpad]
  u16* encW1T = (u16*)alloc((size_t)1024*320*2);
  u16* encW2T = (u16*)alloc((size_t)1024*1024*2);
  u16* kfW1T  = (u16*)alloc((size_t)1024*64*2);
  u16* kfW2T  = (u16*)alloc((size_t)1024*1024*2);
  u16* WqT    = (u16*)alloc((size_t)8*1024*1024*2);
  u16* kvT    = (u16*)alloc((size_t)8*2048*1024*2);   // per layer: [Wk^T ; Wv^T]
  u16* WoT    = (u16*)alloc((size_t)8*1024*1024*2);
  u16* F1T    = (u16*)alloc((size_t)8*4096*1024*2);
  u16* F2T    = (u16*)alloc((size_t)8*1024*4096*2);
  u16* pdW1T  = (u16*)alloc((size_t)1024*1024*2);
  u16* pdW2T  = (u16*)alloc((size_t)128*1024*2);
  u16* gW1T   = (u16*)alloc((size_t)512*64*2);
  u16* gW2T   = (u16*)alloc((size_t)512*512*2);
  u16* gW3T   = (u16*)alloc((size_t)128*512*2);
  u16* md0T   = (u16*)alloc((size_t)8*1024*1024*2);   // [8192,1024] rows=e*1024+n
  u16* md1T   = (u16*)alloc((size_t)8*1024*1024*2);
  u16* md2T   = (u16*)alloc((size_t)8*256*1024*2);    // [2048,1024]

  // activations
  float* x    = (float*)alloc((size_t)NT*1024*4);   // residual stream
  float* rel  = (float*)alloc((size_t)384*64*4);
  u16*   kp   = (u16*)  alloc((size_t)256*64*2);
  u16*   kf1  = (u16*)  alloc((size_t)256*1024*2);
  float* kfe  = (float*)alloc((size_t)256*1024*4);
  u16*   hk   = (u16*)  alloc((size_t)384*1024*2);
  float* kvb  = (float*)alloc((size_t)8*2048*4);    // concat K/V bias
  float* kvbuf= (float*)alloc((size_t)384*2048*4);
  u16*   phbf = (u16*)  alloc((size_t)NT*64*2);
  float* glog = (float*)alloc((size_t)NT*8*4);
  float* gate = (float*)alloc((size_t)NT*8*4);
  u16*   xin  = (u16*)  alloc((size_t)NT*320*2);
  u16*   s1   = (u16*)  alloc((size_t)NT*1024*2);   // h_bf / xf_bf / y1_bf
  float* s2   = (float*)alloc((size_t)NT*1024*4);   // q f32
  u16*   s3   = (u16*)  alloc((size_t)NT*1024*2);   // o_bf / pd1 / gh1 / y0_bf
  u16*   s4   = (u16*)  alloc((size_t)NT*4096*2);   // f1_bf / gh2 / MoE C half 0
  u16*   s5   = (u16*)  alloc((size_t)NT*4096*2);   // MoE C half 1

  float* outY = (float*)d_out;              // [NT,256]
  float* outP = outY + (size_t)NT*256;      // [NT,16]

  auto g64 = [&](const u16* A, const u16* Bt, const float* bias, int biasN,
                 float* Cf, int ldc, int Nf, int accum,
                 u16* Cb, int ldcb, int Nb, int M, int K, int Npad, int act,
                 const float* radd) {
    gemm64<<<dim3(M/64, Npad/128), 256, 0, stream>>>(
        A, Bt, bias, biasN, Cf, ldc, Nf, accum, Cb, ldcb, Nb, K, act, radd);
  };
  auto g128 = [&](const u16* A, const u16* Bt, const float* bias, int biasN,
                  float* Cf, int ldc, int Nf, int accum,
                  u16* Cb, int ldcb, int Nb, int M, int K, int Npad, int act) {
    gemm128<<<dim3(M/128, Npad/128), 256, 0, stream>>>(
        A, Bt, bias, biasN, Cf, ldc, Nf, accum, Cb, ldcb, Nb, K, act);
  };

  // ---- merged weight conversion/transposition: ONE dispatch ----
  TrTable T;
  int tn = 0, toff = 0;
  auto addtr = [&](const float* s_, u16* d_, int K, int N, int Kp, int Np,
                   int batch, long dstride) {
    TrDesc& e = T.d[tn++];
    e.src = s_; e.dst = d_; e.K = K; e.N = N; e.Kp = Kp; e.Np = Np;
    e.tilesX = (Np + 63) / 64;
    e.perBatch = e.tilesX * ((Kp + 63) / 64);
    e.batch = batch; e.tileOff = toff;
    e.sstride = (long)K * N; e.dstride = dstride;
    toff += e.perBatch * batch;
  };
  addtr(enc_W1, encW1T, 273, 1024, 320, 1024, 1, (long)1024*320);
  addtr(enc_W2, encW2T, 1024, 1024, 1024, 1024, 1, (long)1024*1024);
  addtr(kf_W1,  kfW1T,  2, 1024, 64, 1024, 1, (long)1024*64);
  addtr(kf_W2,  kfW2T,  1024, 1024, 1024, 1024, 1, (long)1024*1024);
  addtr(att_Wq, WqT, 1024, 1024, 1024, 1024, 8, (long)1024*1024);
  addtr(att_Wk, kvT,                      1024, 1024, 1024, 1024, 8, (long)2048*1024);
  addtr(att_Wv, kvT + (size_t)1024*1024,  1024, 1024, 1024, 1024, 8, (long)2048*1024);
  addtr(att_Wo, WoT, 1024, 1024, 1024, 1024, 8, (long)1024*1024);
  addtr(pff_W1, F1T, 1024, 4096, 1024, 4096, 8, (long)4096*1024);
  addtr(pff_W2, F2T, 4096, 1024, 4096, 1024, 8, (long)1024*4096);
  addtr(pd_W1,  pdW1T, 1024, 1024, 1024, 1024, 1, (long)1024*1024);
  addtr(pd_W2,  pdW2T, 1024, 16, 1024, 128, 1, (long)128*1024);
  addtr(g_W1,   gW1T, 16, 512, 64, 512, 1, (long)512*64);
  addtr(g_W2,   gW2T, 512, 512, 512, 512, 1, (long)512*512);
  addtr(g_W3,   gW3T, 512, 8, 512, 128, 1, (long)128*512);
  addtr(md_W0,  md0T, 1024, 1024, 1024, 1024, 8, (long)1024*1024);
  addtr(md_W1,  md1T, 1024, 1024, 1024, 1024, 8, (long)1024*1024);
  addtr(md_W2,  md2T, 1024, 256, 1024, 256, 8, (long)256*1024);
  T.n = tn;
  transpose_all<<<toff, 256, 0, stream>>>(T);

  // ---- small precompute ----
  build_xin<<<(NT*320 + 255)/256, 256, 0, stream>>>(motion, phase, xin);
  build_kp_kvb<<<(256*64 + 8*2048 + 255)/256, 256, 0, stream>>>(kp, att_bk, att_bv, kvb);
  relpos<<<384, 64, 0, stream>>>(rp_W1, rp_b1, rp_W2, rp_b2, rel);

  // ---- keyframe embedding (before enc2: its epilogue adds kfe) ----
  g64(kp,  kfW1T, kf_b1, 1024, nullptr,0,0,0, kf1,1024,1024, 256, 64, 1024, 2, nullptr);
  g64(kf1, kfW2T, kf_b2, 1024, kfe,1024,1024,0, nullptr,0,0, 256, 1024, 1024, 0, nullptr);
  // ---- encoder (enc2 fuses + kfe[t] row-broadcast) ----
  g64(xin, encW1T, enc_b1, 1024, nullptr,0,0,0, s1,1024,1024, NT, 320, 1024, 2, nullptr);
  g64(s1,  encW2T, enc_b2, 1024, x,1024,1024,0, nullptr,0,0, NT, 1024, 1024, 2, kfe);

  // ---- transformer layers ----
  for (int l = 0; l < 8; ++l) {
    const size_t w1 = (size_t)l*1024*1024;
    const size_t wf = (size_t)l*4096*1024;
    ln_bf16<<<NT, 256, 0, stream>>>(x, att_ln_g + l*1024, att_ln_b + l*1024, s1, hk);
    g64(s1, WqT + w1, att_bq + l*1024, 1024, s2,1024,1024,0, nullptr,0,0, NT, 1024, 1024, 0, nullptr);
    g64(hk, kvT + (size_t)l*2048*1024, kvb + l*2048, 2048,
        kvbuf,2048,2048,0, nullptr,0,0, 384, 1024, 2048, 0, nullptr);
    attn11<<<NT, 256, 0, stream>>>(s2, kvbuf, rel, s3);
    g64(s3, WoT + w1, att_bo + l*1024, 1024, x,1024,1024,1, nullptr,0,0, NT, 1024, 1024, 0, nullptr);
    ln_bf16<<<NT, 256, 0, stream>>>(x, pff_ln_g + l*1024, pff_ln_b + l*1024, s1, nullptr);
    g128(s1, F1T + wf, pff_b1 + l*4096, 4096, nullptr,0,0,0, s4,4096,4096, NT, 1024, 4096, 1);
    g64(s4, F2T + wf, pff_b2 + l*1024, 1024, x,1024,1024,1, nullptr,0,0, NT, 4096, 1024, 0, nullptr);
  }

  // ---- final LN + phase decoder ----
  ln_bf16<<<NT, 256, 0, stream>>>(x, fin_ln_g, fin_ln_b, s1, nullptr);   // xf_bf
  g64(s1, pdW1T, pd_b1, 1024, nullptr,0,0,0, s3,1024,1024, NT, 1024, 1024, 2, nullptr);
  g64(s3, pdW2T, pd_b2, 16, outP,16,16,0, phbf,64,64, NT, 1024, 128, 0, nullptr);

  // ---- gating ----
  g64(phbf, gW1T, g_b1, 512, nullptr,0,0,0, s3,512,512, NT, 64, 512, 2, nullptr);
  g64(s3,   gW2T, g_b2, 512, nullptr,0,0,0, s4,512,512, NT, 512, 512, 2, nullptr);
  g64(s4,   gW3T, g_b3, 8,  glog,8,8,0, nullptr,0,0, NT, 512, 128, 0, nullptr);
  softmax8<<<(NT + 255)/256, 256, 0, stream>>>(glog, gate);

  // ---- mixture-of-experts decoder (experts concatenated along N) ----
  const int BL2 = (int)(((long)NT*256 + 255)/256);
  // level 0: x(s1) -> y0(s3)
  g128(s1, md0T,                     md_b0,        4096, nullptr,0,0,0, s4,4096,4096, NT, 1024, 4096, 0);
  g128(s1, md0T + (size_t)4096*1024, md_b0 + 4096, 4096, nullptr,0,0,0, s5,4096,4096, NT, 1024, 4096, 0);
  moe_blend2<<<BL2, 256, 0, stream>>>(s4, s5, gate, s3);
  // level 1: y0(s3) -> y1(s1)
  g128(s3, md1T,                     md_b1,        4096, nullptr,0,0,0, s4,4096,4096, NT, 1024, 4096, 0);
  g128(s3, md1T + (size_t)4096*1024, md_b1 + 4096, 4096, nullptr,0,0,0, s5,4096,4096, NT, 1024, 4096, 0);
  moe_blend2<<<BL2, 256, 0, stream>>>(s4, s5, gate, s1);
  // level 2: y1(s1) -> outY
  g128(s1, md2T, md_b2, 2048, nullptr,0,0,0, s4,2048,2048, NT, 1024, 2048, 0);
  moe_blend_out<<<(int)(((long)NT*64 + 255)/256), 256, 0, stream>>>(s4, gate, outY);
}

// Round 16
// 2942.818 us; speedup vs baseline: 1.0516x; 1.0204x over previous
//
#include <hip/hip_runtime.h>
#include <stdint.h>

typedef unsigned short u16;
typedef __attribute__((ext_vector_type(4))) float f32x4;
typedef __attribute__((ext_vector_type(8))) __bf16 bf16x8;

#define NT 6144     // B*T
#define TT 192
#define PRELU_A 0.25f

__device__ __forceinline__ u16 f2bf(float f) {
  unsigned u = __float_as_uint(f);
  u += 0x7fffu + ((u >> 16) & 1u);
  return (u16)(u >> 16);
}
__device__ __forceinline__ float bf2f(u16 u) {
  return __uint_as_float(((unsigned)u) << 16);
}

__device__ __forceinline__ void gload16(const u16* g, __bf16* l) {
  auto* l3 = reinterpret_cast<__attribute__((address_space(3))) __bf16*>(
      reinterpret_cast<uintptr_t>(l));
  const auto* g1 = reinterpret_cast<const __attribute__((address_space(1))) u16*>(
      reinterpret_cast<uintptr_t>(g));
  __builtin_amdgcn_global_load_lds(g1, l3, 16, 0, 0);
}

// XCD-contiguous (m204 bijective) + supertile decode (R14-verified).
__device__ __forceinline__ void xcd_remap(int& bx, int& by)
{
  const int gx = gridDim.x, gy = gridDim.y;
  const int nwg = gx * gy;
  const int f = blockIdx.y * gx + blockIdx.x;
  const int q = nwg >> 3, r = nwg & 7;
  const int xcd = f & 7, s = f >> 3;
  const int w = (xcd < r ? xcd*(q+1) : r*(q+1) + (xcd-r)*q) + s;
  const int CX = ((gx & 7) == 0) ? (gx >> 3) : 1;
  const int per = gy * CX;
  const int c = w / per, rr = w - c*per;
  bx = c*CX + (rr % CX);
  by = rr / CX;
}

// ---------------- merged transpose: all weights in ONE dispatch --------------
// R15 PMC: scalar u16 stores (2B/lane) made this instruction-width-bound
// (230us @ 2.15TB/s, 27% HBM). Vectorized: float4 loads + ds_write_b128 on
// full tiles, ushort4 (8B/lane) stores ALWAYS (Kp/Np are multiples of 64 so
// the padded dst tile is always fully in-bounds; pads were zero-filled on
// the load side).
struct TrDesc {
  const float* src; u16* dst;
  int K, N, Kp, Np;
  int tilesX, perBatch, batch, tileOff;
  long sstride, dstride;
};
struct TrTable { TrDesc d[18]; int n; };

__global__ __launch_bounds__(256)
void transpose_all(TrTable T)
{
  __shared__ float tile[64][65];
  const int bid = blockIdx.x;
  TrDesc de;
  #pragma unroll 1
  for (int i = 0; i < T.n; ++i) {
    const TrDesc& e = T.d[i];
    if (bid >= e.tileOff && bid < e.tileOff + e.perBatch * e.batch) { de = e; break; }
  }
  const int local = bid - de.tileOff;
  const int z = local / de.perBatch;
  const int rem = local - z * de.perBatch;
  const int ty = rem / de.tilesX;
  const int tx = rem - ty * de.tilesX;
  const float* src = de.src + (long)z * de.sstride;
  u16* dst = de.dst + (long)z * de.dstride;
  const int kt = ty * 64, nt2 = tx * 64;

  if (kt + 64 <= de.K && nt2 + 64 <= de.N) {
    // full interior tile: float4 loads, ds_write_b128
    #pragma unroll
    for (int i = 0; i < 4; ++i) {
      const int flat = threadIdx.x + i*256;       // 0..1023
      const int kl = flat >> 4, ng = flat & 15;
      const float4 v = *(const float4*)(src + (long)(kt + kl)*de.N + nt2 + ng*4);
      *(float4*)&tile[kl][ng*4] = v;
    }
  } else {
    #pragma unroll
    for (int i = 0; i < 16; ++i) {
      int idx = threadIdx.x + i*256;
      int kl = idx >> 6, nl = idx & 63;
      int k = kt + kl, n = nt2 + nl;
      tile[kl][nl] = (k < de.K && n < de.N) ? src[(long)k*de.N + n] : 0.f;
    }
  }
  __syncthreads();
  // store: ushort4 = 4 consecutive k of one n column (always in-bounds: Kp,Np %64==0)
  #pragma unroll
  for (int i = 0; i < 4; ++i) {
    const int flat = threadIdx.x + i*256;         // 0..1023
    const int nl = flat >> 4, kg = flat & 15;
    ushort4 o;
    o.x = f2bf(tile[kg*4 + 0][nl]);
    o.y = f2bf(tile[kg*4 + 1][nl]);
    o.z = f2bf(tile[kg*4 + 2][nl]);
    o.w = f2bf(tile[kg*4 + 3][nl]);
    *(ushort4*)(dst + (long)(nt2 + nl)*de.Kp + kt + kg*4) = o;
  }
}

// ---------------- shared epilogue (COMPILE-TIME MR/HM — rule #20) ------------
// radd: optional row-broadcast add (v += radd[(grow%TT)*1024 + gcol]) AFTER act.
template<int MR, int HM>
__device__ __forceinline__ void epilogue_store(
    f32x4 (&acc)[MR][4], long arow0, long brow0, int wm, int wn, int lane,
    const float* bias, int biasN,
    float* Cf, int ldc, int Nf, int accum,
    u16* Cb, int ldcb, int Nb, int act, const float* radd)
{
  const int rbase = wm*HM + ((lane >> 4) << 2);
  const int cbase = wn*64 + (lane & 15);
  #pragma unroll
  for (int m = 0; m < MR; ++m) {
    #pragma unroll
    for (int n = 0; n < 4; ++n) {
      const long gcol = brow0 + cbase + n*16;
      const float bv = (bias && gcol < biasN) ? bias[gcol] : 0.f;
      #pragma unroll
      for (int r = 0; r < 4; ++r) {
        const long grow = arow0 + rbase + m*16 + r;
        float v = acc[m][n][r] + bv;
        if (act == 1) v = fmaxf(v, 0.f);
        else if (act == 2) v = (v >= 0.f) ? v : PRELU_A * v;
        if (radd) v += radd[(int)(grow % TT)*1024 + gcol];
        if (Cf && gcol < Nf) {
          const long idx = grow * (long)ldc + gcol;
          Cf[idx] = accum ? (Cf[idx] + v) : v;
        }
        if (Cb && gcol < Nb) Cb[grow * (long)ldcb + gcol] = f2bf(v);
      }
    }
  }
}

// ---------------- 64x128 bf16 GEMM, BK=64, ring-2 counted-vmcnt (R9/R11) -----
__global__ __launch_bounds__(256, 3)
void gemm64(const u16* __restrict__ A, const u16* __restrict__ Bt,
            const float* __restrict__ bias, int biasN,
            float* __restrict__ Cf, int ldc, int Nf, int accum,
            u16* __restrict__ Cb, int ldcb, int Nb,
            int K, int act, const float* __restrict__ radd)
{
  __shared__ __bf16 As[2*64*64];
  __shared__ __bf16 Bs[2*128*64];
  const int tid = threadIdx.x;
  const int wid = tid >> 6;
  const int lane = tid & 63;
  const int wm = wid >> 1, wn = wid & 1;
  int bx, by; xcd_remap(bx, by);
  const long arow0 = (long)bx * 64;
  const long brow0 = (long)by * 128;
  const int lr  = lane >> 3;
  const int lko = ((lane & 7) ^ (lane >> 3)) << 3;

  f32x4 acc[2][4];
  #pragma unroll
  for (int m = 0; m < 2; ++m)
    #pragma unroll
    for (int n = 0; n < 4; ++n) acc[m][n] = (f32x4)0.f;

  const int aro = lane & 15;
  const int g = lane >> 4;

  auto stage = [&](int buf, int kt) {
    #pragma unroll
    for (int c = wid; c < 24; c += 4) {
      if (c < 8) gload16(A + (arow0 + c*8 + lr)*K + kt + lko, As + buf*(64*64) + c*512);
      else       gload16(Bt + (brow0 + (c-8)*8 + lr)*K + kt + lko,
                         Bs + buf*(128*64) + (c-8)*512);
    }
  };

  const int nt = K >> 6;
  stage(0, 0);
  for (int t = 0; t < nt; ++t) {
    if (t + 1 < nt) {
      stage((t+1) & 1, (t+1) << 6);
      asm volatile("s_waitcnt vmcnt(6)" ::: "memory");
    } else {
      asm volatile("s_waitcnt vmcnt(0)" ::: "memory");
    }
    __builtin_amdgcn_s_barrier();
    asm volatile("" ::: "memory");
    const __bf16* Ab = As + (t&1)*(64*64);
    const __bf16* Bb = Bs + (t&1)*(128*64);
    #pragma unroll
    for (int kk = 0; kk < 2; ++kk) {
      bf16x8 af[2], bfv[4];
      #pragma unroll
      for (int m = 0; m < 2; ++m) {
        const int R = wm*32 + m*16 + aro;
        af[m] = *(const bf16x8*)(Ab + R*64 + (((kk*4 + g) ^ (R & 7)) << 3));
      }
      #pragma unroll
      for (int n = 0; n < 4; ++n) {
        const int R = wn*64 + n*16 + aro;
        bfv[n] = *(const bf16x8*)(Bb + R*64 + (((kk*4 + g) ^ (R & 7)) << 3));
      }
      #pragma unroll
      for (int m = 0; m < 2; ++m)
        #pragma unroll
        for (int n = 0; n < 4; ++n)
          acc[m][n] = __builtin_amdgcn_mfma_f32_16x16x32_bf16(af[m], bfv[n], acc[m][n], 0, 0, 0);
    }
    asm volatile("" ::: "memory");
    __builtin_amdgcn_s_barrier();    // readers done before next stage overwrites
  }
  epilogue_store<2,32>(acc, arow0, brow0, wm, wn, lane,
                       bias, biasN, Cf, ldc, Nf, accum, Cb, ldcb, Nb, act, radd);
}

// ---------------- 128x128 bf16 GEMM, BK=32, ring-2, 32KB LDS (R13) -----------
__global__ __launch_bounds__(256, 4)
void gemm128(const u16* __restrict__ A, const u16* __restrict__ Bt,
             const float* __restrict__ bias, int biasN,
             float* __restrict__ Cf, int ldc, int Nf, int accum,
             u16* __restrict__ Cb, int ldcb, int Nb,
             int K, int act)
{
  __shared__ __bf16 As[2*128*32];
  __shared__ __bf16 Bs[2*128*32];
  const int tid = threadIdx.x;
  const int wid = tid >> 6;
  const int lane = tid & 63;
  const int wm = wid >> 1, wn = wid & 1;
  int bx, by; xcd_remap(bx, by);
  const long arow0 = (long)bx * 128;
  const long brow0 = (long)by * 128;
  const int srow = lane >> 2;
  const int skoff = ((lane & 3) ^ ((lane >> 3) & 3)) << 3;

  f32x4 acc[4][4];
  #pragma unroll
  for (int m = 0; m < 4; ++m)
    #pragma unroll
    for (int n = 0; n < 4; ++n) acc[m][n] = (f32x4)0.f;

  const int aro = lane & 15;
  const int g = lane >> 4;

  auto stage = [&](int buf, int kt) {
    #pragma unroll
    for (int c = wid; c < 16; c += 4) {
      if (c < 8) gload16(A + (arow0 + c*16 + srow)*K + kt + skoff, As + buf*4096 + c*512);
      else       gload16(Bt + (brow0 + (c-8)*16 + srow)*K + kt + skoff,
                         Bs + buf*4096 + (c-8)*512);
    }
  };

  const int nt = K >> 5;
  stage(0, 0);
  for (int t = 0; t < nt; ++t) {
    if (t + 1 < nt) {
      stage((t+1) & 1, (t+1) << 5);
      asm volatile("s_waitcnt vmcnt(4)" ::: "memory");
    } else {
      asm volatile("s_waitcnt vmcnt(0)" ::: "memory");
    }
    __builtin_amdgcn_s_barrier();
    asm volatile("" ::: "memory");
    const __bf16* Ab = As + (t&1)*4096;
    const __bf16* Bb = Bs + (t&1)*4096;
    bf16x8 af[4], bfv[4];
    #pragma unroll
    for (int m = 0; m < 4; ++m) {
      const int R = wm*64 + m*16 + aro;
      af[m] = *(const bf16x8*)(Ab + R*32 + ((g ^ ((R >> 1) & 3)) << 3));
    }
    #pragma unroll
    for (int n = 0; n < 4; ++n) {
      const int R = wn*64 + n*16 + aro;
      bfv[n] = *(const bf16x8*)(Bb + R*32 + ((g ^ ((R >> 1) & 3)) << 3));
    }
    #pragma unroll
    for (int m = 0; m < 4; ++m)
      #pragma unroll
      for (int n = 0; n < 4; ++n)
        acc[m][n] = __builtin_amdgcn_mfma_f32_16x16x32_bf16(af[m], bfv[n], acc[m][n], 0, 0, 0);
    asm volatile("" ::: "memory");
    __builtin_amdgcn_s_barrier();    // readers done before next stage overwrites
  }
  epilogue_store<4,64>(acc, arow0, brow0, wm, wn, lane,
                       bias, biasN, Cf, ldc, Nf, accum, Cb, ldcb, Nb, act, nullptr);
}

// --- MoE blend (2 half-buffers, H=1024): out = prelu(sum_e gate_e * C_e) ----
__global__ __launch_bounds__(256)
void moe_blend2(const u16* __restrict__ C0, const u16* __restrict__ C1,
                const float* __restrict__ gate, u16* __restrict__ outb)
{
  const long idx = (long)blockIdx.x*256 + threadIdx.x;   // float4 over [NT,1024]
  if (idx >= (long)NT*256) return;
  const long t = idx >> 8;
  const int h = (int)(idx & 255) << 2;
  float sx = 0.f, sy = 0.f, sz = 0.f, sw = 0.f;
  #pragma unroll
  for (int j = 0; j < 4; ++j) {
    const float gv = gate[t*8 + j];
    const ushort4 c4 = *(const ushort4*)(C0 + t*4096 + j*1024 + h);
    sx += gv * bf2f(c4.x); sy += gv * bf2f(c4.y);
    sz += gv * bf2f(c4.z); sw += gv * bf2f(c4.w);
  }
  #pragma unroll
  for (int j = 0; j < 4; ++j) {
    const float gv = gate[t*8 + 4 + j];
    const ushort4 c4 = *(const ushort4*)(C1 + t*4096 + j*1024 + h);
    sx += gv * bf2f(c4.x); sy += gv * bf2f(c4.y);
    sz += gv * bf2f(c4.z); sw += gv * bf2f(c4.w);
  }
  sx = (sx >= 0.f) ? sx : PRELU_A * sx;
  sy = (sy >= 0.f) ? sy : PRELU_A * sy;
  sz = (sz >= 0.f) ? sz : PRELU_A * sz;
  sw = (sw >= 0.f) ? sw : PRELU_A * sw;
  ushort4 o; o.x = f2bf(sx); o.y = f2bf(sy); o.z = f2bf(sz); o.w = f2bf(sw);
  *(ushort4*)(outb + t*1024 + h) = o;
}

// --- MoE final blend (level 2, H=256, 8 experts contiguous) -> f32 out -------
__global__ __launch_bounds__(256)
void moe_blend_out(const u16* __restrict__ C, const float* __restrict__ gate,
                   float* __restrict__ outf)
{
  const long idx = (long)blockIdx.x*256 + threadIdx.x;   // float4 over [NT,256]
  if (idx >= (long)NT*64) return;
  const long t = idx >> 6;
  const int h = (int)(idx & 63) << 2;
  float sx = 0.f, sy = 0.f, sz = 0.f, sw = 0.f;
  #pragma unroll
  for (int j = 0; j < 8; ++j) {
    const float gv = gate[t*8 + j];
    const ushort4 c4 = *(const ushort4*)(C + t*2048 + j*256 + h);
    sx += gv * bf2f(c4.x); sy += gv * bf2f(c4.y);
    sz += gv * bf2f(c4.z); sw += gv * bf2f(c4.w);
  }
  float4 o; o.x = sx; o.y = sy; o.z = sz; o.w = sw;
  ((float4*)(outf + t*256))[h >> 2] = o;
}

// ---------------- small helper kernels --------------------------------------
__global__ __launch_bounds__(256)
void build_xin(const float* __restrict__ motion, const float* __restrict__ phase,
               u16* __restrict__ xin)   // [NT, 320] zero-padded
{
  const long idx = (long)blockIdx.x*256 + threadIdx.x;
  if (idx >= (long)NT*320) return;
  const int c = (int)(idx % 320);
  const long row = idx / 320;
  const int t = (int)(row % TT);
  const bool dm = (t < 10) || (t == TT-1);
  float v;
  if (c < 256)       v = dm ? motion[row*256 + c] : 0.f;
  else if (c == 256) v = dm ? 1.f : 0.f;
  else if (c < 273)  v = dm ? phase[row*16 + (c-257)] : 0.f;
  else               v = 0.f;
  xin[idx] = f2bf(v);
}

// kp [256,64] zero-padded + concat K/V bias [8][2048] in one launch
__global__ __launch_bounds__(256)
void build_kp_kvb(u16* __restrict__ kp,
                  const float* __restrict__ bk, const float* __restrict__ bv,
                  float* __restrict__ kvb)
{
  const int idx = blockIdx.x*256 + threadIdx.x;
  if (idx < 256*64) {
    const int r = idx / 64, c = idx % 64;
    float v = 0.f;
    if (r < TT) {
      if (c == 0) v = (float)(r - 9);
      else if (c == 1) v = (float)(TT-1 - r);
    }
    kp[idx] = f2bf(v);
  } else {
    const int j = idx - 256*64;
    if (j < 8*2048) {
      const int l = j >> 11, c = j & 2047;
      kvb[j] = (c < 1024) ? bk[l*1024 + c] : bv[l*1024 + c - 1024];
    }
  }
}

__global__ __launch_bounds__(64)
void relpos(const float* __restrict__ W1, const float* __restrict__ b1,
            const float* __restrict__ W2, const float* __restrict__ b2,
            float* __restrict__ rel)
{
  const int r = blockIdx.x;      // 0..383 (rows >=383 zeroed, never read)
  const int d = threadIdx.x;
  __shared__ float h[64];
  const float rp = (float)(r - (TT-1));
  float hv = rp * W1[d] + b1[d];
  hv = (hv >= 0.f) ? hv : PRELU_A * hv;
  h[d] = hv;
  __syncthreads();
  if (r < 2*TT - 1) {
    float o = b2[d];
    for (int j = 0; j < 64; ++j) o += h[j] * W2[j*64 + d];
    rel[r*64 + d] = o;
  } else {
    rel[r*64 + d] = 0.f;
  }
}

// LN -> bf16; optionally dual-writes keyframe rows into hk[b*11+j].
__global__ __launch_bounds__(256)
void ln_bf16(const float* __restrict__ x, const float* __restrict__ g,
             const float* __restrict__ b, u16* __restrict__ out,
             u16* __restrict__ hk)
{
  const long row = blockIdx.x;
  const float4 v = ((const float4*)(x + row*1024))[threadIdx.x];
  float s  = v.x + v.y + v.z + v.w;
  float s2 = v.x*v.x + v.y*v.y + v.z*v.z + v.w*v.w;
  #pragma unroll
  for (int m = 32; m; m >>= 1) { s += __shfl_xor(s, m); s2 += __shfl_xor(s2, m); }
  __shared__ float red[8];
  const int wid = threadIdx.x >> 6;
  if ((threadIdx.x & 63) == 0) { red[wid] = s; red[wid+4] = s2; }
  __syncthreads();
  s  = red[0] + red[1] + red[2] + red[3];
  s2 = red[4] + red[5] + red[6] + red[7];
  const float mean = s * (1.f/1024.f);
  const float var  = fmaxf(s2 * (1.f/1024.f) - mean*mean, 0.f);
  const float rs   = rsqrtf(var + 1e-5f);
  const float4 gg = ((const float4*)g)[threadIdx.x];
  const float4 bb = ((const float4*)b)[threadIdx.x];
  ushort4 o;
  o.x = f2bf((v.x-mean)*rs*gg.x + bb.x);
  o.y = f2bf((v.y-mean)*rs*gg.y + bb.y);
  o.z = f2bf((v.z-mean)*rs*gg.z + bb.z);
  o.w = f2bf((v.w-mean)*rs*gg.w + bb.w);
  ((ushort4*)(out + row*1024))[threadIdx.x] = o;
  if (hk) {
    const int t = (int)(row % TT);
    if (t < 10 || t == TT-1) {
      const int bidx = (int)(row / TT);
      const int j = (t < 10) ? t : 10;
      ((ushort4*)(hk + (long)(bidx*11 + j)*1024))[threadIdx.x] = o;
    }
  }
}

// 11-key masked attention: one BLOCK (256 thr) per row (R9-verified).
__global__ __launch_bounds__(256)
void attn11(const float* __restrict__ q, const float* __restrict__ kv,
            const float* __restrict__ rel, u16* __restrict__ o)
{
  const int row = blockIdx.x;
  const int b = row / TT, i = row - b*TT;
  const int t = threadIdx.x;
  const int n = t >> 4;         // head
  const int dq = t & 15;        // float4 slot within head
  const float4 qv = *(const float4*)(q + (long)row*1024 + t*4);
  float e[11];
  float mx = -1e30f;
  #pragma unroll
  for (int j = 0; j < 11; ++j) {
    const int kf = (j < 10) ? j : (TT-1);
    const float4 k4 = *(const float4*)(kv + (long)(b*11 + j)*2048 + n*64 + dq*4);
    const float4 r4 = *(const float4*)(rel + (kf - i + TT-1)*64 + dq*4);
    float s = qv.x*(k4.x+r4.x) + qv.y*(k4.y+r4.y)
            + qv.z*(k4.z+r4.z) + qv.w*(k4.w+r4.w);
    s += __shfl_xor(s, 1); s += __shfl_xor(s, 2);
    s += __shfl_xor(s, 4); s += __shfl_xor(s, 8);
    e[j] = s * 0.125f;           // 1/sqrt(64)
    mx = fmaxf(mx, e[j]);
  }
  float den = 0.f;
  #pragma unroll
  for (int j = 0; j < 11; ++j) { e[j] = __expf(e[j] - mx); den += e[j]; }
  const float inv = 1.f / den;
  float ax = 0.f, ay = 0.f, az = 0.f, aw = 0.f;
  #pragma unroll
  for (int j = 0; j < 11; ++j) {
    const float4 v4 = *(const float4*)(kv + (long)(b*11 + j)*2048 + 1024 + n*64 + dq*4);
    ax += e[j]*v4.x; ay += e[j]*v4.y; az += e[j]*v4.z; aw += e[j]*v4.w;
  }
  ushort4 ov;
  ov.x = f2bf(ax*inv); ov.y = f2bf(ay*inv); ov.z = f2bf(az*inv); ov.w = f2bf(aw*inv);
  *(ushort4*)(o + (long)row*1024 + t*4) = ov;
}

__global__ __launch_bounds__(256)
void softmax8(const float* __restrict__ lg, float* __restrict__ gate)
{
  const int t = blockIdx.x*256 + threadIdx.x;
  if (t >= NT) return;
  float v[8], mx = -1e30f;
  #pragma unroll
  for (int e = 0; e < 8; ++e) { v[e] = lg[t*8 + e]; mx = fmaxf(mx, v[e]); }
  float den = 0.f;
  #pragma unroll
  for (int e = 0; e < 8; ++e) { v[e] = __expf(v[e] - mx); den += v[e]; }
  const float inv = 1.f / den;
  #pragma unroll
  for (int e = 0; e < 8; ++e) gate[t*8 + e] = v[e] * inv;
}

// ---------------- host ------------------------------------------------------
extern "C" void kernel_launch(void* const* d_in, const int* in_sizes, int n_in,
                              void* d_out, int out_size, void* d_ws, size_t ws_size,
                              hipStream_t stream)
{
  (void)in_sizes; (void)n_in; (void)out_size; (void)ws_size;
  const float* motion  = (const float*)d_in[0];
  const float* phase   = (const float*)d_in[1];
  const float* enc_W1  = (const float*)d_in[2];
  const float* enc_b1  = (const float*)d_in[3];
  const float* enc_W2  = (const float*)d_in[4];
  const float* enc_b2  = (const float*)d_in[5];
  const float* kf_W1   = (const float*)d_in[6];
  const float* kf_b1   = (const float*)d_in[7];
  const float* kf_W2   = (const float*)d_in[8];
  const float* kf_b2   = (const float*)d_in[9];
  const float* rp_W1   = (const float*)d_in[10];
  const float* rp_b1   = (const float*)d_in[11];
  const float* rp_W2   = (const float*)d_in[12];
  const float* rp_b2   = (const float*)d_in[13];
  const float* att_Wq  = (const float*)d_in[14];
  const float* att_bq  = (const float*)d_in[15];
  const float* att_Wk  = (const float*)d_in[16];
  const float* att_bk  = (const float*)d_in[17];
  const float* att_Wv  = (const float*)d_in[18];
  const float* att_bv  = (const float*)d_in[19];
  const float* att_Wo  = (const float*)d_in[20];
  const float* att_bo  = (const float*)d_in[21];
  const float* att_ln_g = (const float*)d_in[22];
  const float* att_ln_b = (const float*)d_in[23];
  const float* pff_W1  = (const float*)d_in[24];
  const float* pff_b1  = (const float*)d_in[25];
  const float* pff_W2  = (const float*)d_in[26];
  const float* pff_b2  = (const float*)d_in[27];
  const float* pff_ln_g = (const float*)d_in[28];
  const float* pff_ln_b = (const float*)d_in[29];
  const float* fin_ln_g = (const float*)d_in[30];
  const float* fin_ln_b = (const float*)d_in[31];
  const float* pd_W1   = (const float*)d_in[32];
  const float* pd_b1   = (const float*)d_in[33];
  const float* pd_W2   = (const float*)d_in[34];
  const float* pd_b2   = (const float*)d_in[35];
  const float* g_W1    = (const float*)d_in[36];
  const float* g_b1    = (const float*)d_in[37];
  const float* g_W2    = (const float*)d_in[38];
  const float* g_b2    = (const float*)d_in[39];
  const float* g_W3    = (const float*)d_in[40];
  const float* g_b3    = (const float*)d_in[41];
  const float* md_W0   = (const float*)d_in[42];
  const float* md_b0   = (const float*)d_in[43];
  const float* md_W1   = (const float*)d_in[44];
  const float* md_b1   = (const float*)d_in[45];
  const float* md_W2   = (const float*)d_in[46];
  const float* md_b2   = (const float*)d_in[47];

  char* wsp = (char*)d_ws;
  size_t off = 0;
  auto alloc = [&](size_t bytes) -> char* {
    char* p = wsp + off;
    off += (bytes + 255) & ~(size_t)255;
    return p;
  };

  // bf16 transposed weights [Npad, Kpad]
  u16* encW1T = (u16*)alloc((size_t)1024*320*2);
  u16* encW2T = (u16*)alloc((size_t)1024*1024*2);
  u16* kfW1T  = (u16*)alloc((size_t)1024*64*2);
  u16* kfW2T  = (u16*)alloc((size_t)1024*1024*2);
  u16* WqT    = (u16*)alloc((size_t)8*1024*1024*2);
  u16* kvT    = (u16*)alloc((size_t)8*2048*1024*2);   // per layer: [Wk^T ; Wv^T]
  u16* WoT    = (u16*)alloc((size_t)8*1024*1024*2);
  u16* F1T    = (u16*)alloc((size_t)8*4096*1024*2);
  u16* F2T    = (u16*)alloc((size_t)8*1024*4096*2);
  u16* pdW1T  = (u16*)alloc((size_t)1024*1024*2);
  u16* pdW2T  = (u16*)alloc((size_t)128*1024*2);
  u16* gW1T   = (u16*)alloc((size_t)512*64*2);
  u16* gW2T   = (u16*)alloc((size_t)512*512*2);
  u16* gW3T   = (u16*)alloc((size_t)128*512*2);
  u16* md0T   = (u16*)alloc((size_t)8*1024*1024*2);   // [8192,1024] rows=e*1024+n
  u16* md1T   = (u16*)alloc((size_t)8*1024*1024*2);
  u16* md2T   = (u16*)alloc((size_t)8*256*1024*2);    // [2048,1024]

  // activations
  float* x    = (float*)alloc((size_t)NT*1024*4);   // residual stream
  float* rel  = (float*)alloc((size_t)384*64*4);
  u16*   kp   = (u16*)  alloc((size_t)256*64*2);
  u16*   kf1  = (u16*)  alloc((size_t)256*1024*2);
  float* kfe  = (float*)alloc((size_t)256*1024*4);
  u16*   hk   = (u16*)  alloc((size_t)384*1024*2);
  float* kvb  = (float*)alloc((size_t)8*2048*4);    // concat K/V bias
  float* kvbuf= (float*)alloc((size_t)384*2048*4);
  u16*   phbf = (u16*)  alloc((size_t)NT*64*2);
  float* glog = (float*)alloc((size_t)NT*8*4);
  float* gate = (float*)alloc((size_t)NT*8*4);
  u16*   xin  = (u16*)  alloc((size_t)NT*320*2);
  u16*   s1   = (u16*)  alloc((size_t)NT*1024*2);   // h_bf / xf_bf / y1_bf
  float* s2   = (float*)alloc((size_t)NT*1024*4);   // q f32
  u16*   s3   = (u16*)  alloc((size_t)NT*1024*2);   // o_bf / pd1 / gh1 / y0_bf
  u16*   s4   = (u16*)  alloc((size_t)NT*4096*2);   // f1_bf / gh2 / MoE C half 0
  u16*   s5   = (u16*)  alloc((size_t)NT*4096*2);   // MoE C half 1

  float* outY = (float*)d_out;              // [NT,256]
  float* outP = outY + (size_t)NT*256;      // [NT,16]

  auto g64 = [&](const u16* A, const u16* Bt, const float* bias, int biasN,
                 float* Cf, int ldc, int Nf, int accum,
                 u16* Cb, int ldcb, int Nb, int M, int K, int Npad, int act,
                 const float* radd) {
    gemm64<<<dim3(M/64, Npad/128), 256, 0, stream>>>(
        A, Bt, bias, biasN, Cf, ldc, Nf, accum, Cb, ldcb, Nb, K, act, radd);
  };
  auto g128 = [&](const u16* A, const u16* Bt, const float* bias, int biasN,
                  float* Cf, int ldc, int Nf, int accum,
                  u16* Cb, int ldcb, int Nb, int M, int K, int Npad, int act) {
    gemm128<<<dim3(M/128, Npad/128), 256, 0, stream>>>(
        A, Bt, bias, biasN, Cf, ldc, Nf, accum, Cb, ldcb, Nb, K, act);
  };

  // ---- merged weight conversion/transposition: ONE dispatch ----
  TrTable T;
  int tn = 0, toff = 0;
  auto addtr = [&](const float* s_, u16* d_, int K, int N, int Kp, int Np,
                   int batch, long dstride) {
    TrDesc& e = T.d[tn++];
    e.src = s_; e.dst = d_; e.K = K; e.N = N; e.Kp = Kp; e.Np = Np;
    e.tilesX = (Np + 63) / 64;
    e.perBatch = e.tilesX * ((Kp + 63) / 64);
    e.batch = batch; e.tileOff = toff;
    e.sstride = (long)K * N; e.dstride = dstride;
    toff += e.perBatch * batch;
  };
  addtr(enc_W1, encW1T, 273, 1024, 320, 1024, 1, (long)1024*320);
  addtr(enc_W2, encW2T, 1024, 1024, 1024, 1024, 1, (long)1024*1024);
  addtr(kf_W1,  kfW1T,  2, 1024, 64, 1024, 1, (long)1024*64);
  addtr(kf_W2,  kfW2T,  1024, 1024, 1024, 1024, 1, (long)1024*1024);
  addtr(att_Wq, WqT, 1024, 1024, 1024, 1024, 8, (long)1024*1024);
  addtr(att_Wk, kvT,                      1024, 1024, 1024, 1024, 8, (long)2048*1024);
  addtr(att_Wv, kvT + (size_t)1024*1024,  1024, 1024, 1024, 1024, 8, (long)2048*1024);
  addtr(att_Wo, WoT, 1024, 1024, 1024, 1024, 8, (long)1024*1024);
  addtr(pff_W1, F1T, 1024, 4096, 1024, 4096, 8, (long)4096*1024);
  addtr(pff_W2, F2T, 4096, 1024, 4096, 1024, 8, (long)1024*4096);
  addtr(pd_W1,  pdW1T, 1024, 1024, 1024, 1024, 1, (long)1024*1024);
  addtr(pd_W2,  pdW2T, 1024, 16, 1024, 128, 1, (long)128*1024);
  addtr(g_W1,   gW1T, 16, 512, 64, 512, 1, (long)512*64);
  addtr(g_W2,   gW2T, 512, 512, 512, 512, 1, (long)512*512);
  addtr(g_W3,   gW3T, 512, 8, 512, 128, 1, (long)128*512);
  addtr(md_W0,  md0T, 1024, 1024, 1024, 1024, 8, (long)1024*1024);
  addtr(md_W1,  md1T, 1024, 1024, 1024, 1024, 8, (long)1024*1024);
  addtr(md_W2,  md2T, 1024, 256, 1024, 256, 8, (long)256*1024);
  T.n = tn;
  transpose_all<<<toff, 256, 0, stream>>>(T);

  // ---- small precompute ----
  build_xin<<<(NT*320 + 255)/256, 256, 0, stream>>>(motion, phase, xin);
  build_kp_kvb<<<(256*64 + 8*2048 + 255)/256, 256, 0, stream>>>(kp, att_bk, att_bv, kvb);
  relpos<<<384, 64, 0, stream>>>(rp_W1, rp_b1, rp_W2, rp_b2, rel);

  // ---- keyframe embedding (before enc2: its epilogue adds kfe) ----
  g64(kp,  kfW1T, kf_b1, 1024, nullptr,0,0,0, kf1,1024,1024, 256, 64, 1024, 2, nullptr);
  g64(kf1, kfW2T, kf_b2, 1024, kfe,1024,1024,0, nullptr,0,0, 256, 1024, 1024, 0, nullptr);
  // ---- encoder (enc2 fuses + kfe[t] row-broadcast) ----
  g64(xin, encW1T, enc_b1, 1024, nullptr,0,0,0, s1,1024,1024, NT, 320, 1024, 2, nullptr);
  g64(s1,  encW2T, enc_b2, 1024, x,1024,1024,0, nullptr,0,0, NT, 1024, 1024, 2, kfe);

  // ---- transformer layers ----
  for (int l = 0; l < 8; ++l) {
    const size_t w1 = (size_t)l*1024*1024;
    const size_t wf = (size_t)l*4096*1024;
    ln_bf16<<<NT, 256, 0, stream>>>(x, att_ln_g + l*1024, att_ln_b + l*1024, s1, hk);
    g64(s1, WqT + w1, att_bq + l*1024, 1024, s2,1024,1024,0, nullptr,0,0, NT, 1024, 1024, 0, nullptr);
    g64(hk, kvT + (size_t)l*2048*1024, kvb + l*2048, 2048,
        kvbuf,2048,2048,0, nullptr,0,0, 384, 1024, 2048, 0, nullptr);
    attn11<<<NT, 256, 0, stream>>>(s2, kvbuf, rel, s3);
    g64(s3, WoT + w1, att_bo + l*1024, 1024, x,1024,1024,1, nullptr,0,0, NT, 1024, 1024, 0, nullptr);
    ln_bf16<<<NT, 256, 0, stream>>>(x, pff_ln_g + l*1024, pff_ln_b + l*1024, s1, nullptr);
    g128(s1, F1T + wf, pff_b1 + l*4096, 4096, nullptr,0,0,0, s4,4096,4096, NT, 1024, 4096, 1);
    g64(s4, F2T + wf, pff_b2 + l*1024, 1024, x,1024,1024,1, nullptr,0,0, NT, 4096, 1024, 0, nullptr);
  }

  // ---- final LN + phase decoder ----
  ln_bf16<<<NT, 256, 0, stream>>>(x, fin_ln_g, fin_ln_b, s1, nullptr);   // xf_bf
  g64(s1, pdW1T, pd_b1, 1024, nullptr,0,0,0, s3,1024,1024, NT, 1024, 1024, 2, nullptr);
  g64(s3, pdW2T, pd_b2, 16, outP,16,16,0, phbf,64,64, NT, 1024, 128, 0, nullptr);

  // ---- gating ----
  g64(phbf, gW1T, g_b1, 512, nullptr,0,0,0, s3,512,512, NT, 64, 512, 2, nullptr);
  g64(s3,   gW2T, g_b2, 512, nullptr,0,0,0, s4,512,512, NT, 512, 512, 2, nullptr);
  g64(s4,   gW3T, g_b3, 8,  glog,8,8,0, nullptr,0,0, NT, 512, 128, 0, nullptr);
  softmax8<<<(NT + 255)/256, 256, 0, stream>>>(glog, gate);

  // ---- mixture-of-experts decoder (experts concatenated along N) ----
  const int BL2 = (int)(((long)NT*256 + 255)/256);
  // level 0: x(s1) -> y0(s3)
  g128(s1, md0T,                     md_b0,        4096, nullptr,0,0,0, s4,4096,4096, NT, 1024, 4096, 0);
  g128(s1, md0T + (size_t)4096*1024, md_b0 + 4096, 4096, nullptr,0,0,0, s5,4096,4096, NT, 1024, 4096, 0);
  moe_blend2<<<BL2, 256, 0, stream>>>(s4, s5, gate, s3);
  // level 1: y0(s3) -> y1(s1)
  g128(s3, md1T,                     md_b1,        4096, nullptr,0,0,0, s4,4096,4096, NT, 1024, 4096, 0);
  g128(s3, md1T + (size_t)4096*1024, md_b1 + 4096, 4096, nullptr,0,0,0, s5,4096,4096, NT, 1024, 4096, 0);
  moe_blend2<<<BL2, 256, 0, stream>>>(s4, s5, gate, s1);
  // level 2: y1(s1) -> outY
  g128(s1, md2T, md_b2, 2048, nullptr,0,0,0, s4,2048,2048, NT, 1024, 2048, 0);
  moe_blend_out<<<(int)(((long)NT*64 + 255)/256), 256, 0, stream>>>(s4, gate, outY);
}

// Round 17
// 2940.742 us; speedup vs baseline: 1.0524x; 1.0007x over previous
//
#include <hip/hip_runtime.h>
#include <stdint.h>

typedef unsigned short u16;
typedef __attribute__((ext_vector_type(4))) float f32x4;
typedef __attribute__((ext_vector_type(8))) __bf16 bf16x8;

#define NT 6144     // B*T
#define TT 192
#define PRELU_A 0.25f

__device__ __forceinline__ u16 f2bf(float f) {
  unsigned u = __float_as_uint(f);
  u += 0x7fffu + ((u >> 16) & 1u);
  return (u16)(u >> 16);
}
__device__ __forceinline__ float bf2f(u16 u) {
  return __uint_as_float(((unsigned)u) << 16);
}

__device__ __forceinline__ void gload16(const u16* g, __bf16* l) {
  auto* l3 = reinterpret_cast<__attribute__((address_space(3))) __bf16*>(
      reinterpret_cast<uintptr_t>(l));
  const auto* g1 = reinterpret_cast<const __attribute__((address_space(1))) u16*>(
      reinterpret_cast<uintptr_t>(g));
  __builtin_amdgcn_global_load_lds(g1, l3, 16, 0, 0);
}

// XCD-contiguous (m204 bijective) + supertile decode (R14-verified).
__device__ __forceinline__ void xcd_remap(int& bx, int& by)
{
  const int gx = gridDim.x, gy = gridDim.y;
  const int nwg = gx * gy;
  const int f = blockIdx.y * gx + blockIdx.x;
  const int q = nwg >> 3, r = nwg & 7;
  const int xcd = f & 7, s = f >> 3;
  const int w = (xcd < r ? xcd*(q+1) : r*(q+1) + (xcd-r)*q) + s;
  const int CX = ((gx & 7) == 0) ? (gx >> 3) : 1;
  const int per = gy * CX;
  const int c = w / per, rr = w - c*per;
  bx = c*CX + (rr % CX);
  by = rr / CX;
}

// ---------------- merged transpose: all weights in ONE dispatch --------------
// R16 PMC: 7.7M LDS conflicts — with lanes spanning 4 rows x 16 chunks, chunks
// ng and ng+8 of a row share bank ((kl+4ng)%32). R17: lane remap so each
// 32-lane phase spans 4 rows x 8 chunks (write) / 8 kgroups x 4 cols (read):
// per-phase bank = kl_lo + 4*ng_lo, a bijection onto 0..31 -> conflict-free.
// Global stays coalesced (8 consecutive lanes -> consecutive 16B/8B).
struct TrDesc {
  const float* src; u16* dst;
  int K, N, Kp, Np;
  int tilesX, perBatch, batch, tileOff;
  long sstride, dstride;
};
struct TrTable { TrDesc d[18]; int n; };

__global__ __launch_bounds__(256)
void transpose_all(TrTable T)
{
  __shared__ float tile[64][65];
  const int bid = blockIdx.x;
  TrDesc de;
  #pragma unroll 1
  for (int i = 0; i < T.n; ++i) {
    const TrDesc& e = T.d[i];
    if (bid >= e.tileOff && bid < e.tileOff + e.perBatch * e.batch) { de = e; break; }
  }
  const int local = bid - de.tileOff;
  const int z = local / de.perBatch;
  const int rem = local - z * de.perBatch;
  const int ty = rem / de.tilesX;
  const int tx = rem - ty * de.tilesX;
  const float* src = de.src + (long)z * de.sstride;
  u16* dst = de.dst + (long)z * de.dstride;
  const int kt = ty * 64, nt2 = tx * 64;

  if (kt + 64 <= de.K && nt2 + 64 <= de.N) {
    // full interior tile: float4 loads, conflict-free lane remap
    #pragma unroll
    for (int i = 0; i < 4; ++i) {
      const int flat = threadIdx.x + i*256;                    // 10 bits
      const int ng = (flat & 7) | (((flat >> 9) & 1) << 3);    // chunk 0..15
      const int kl = ((flat >> 3) & 7) | (((flat >> 6) & 7) << 3); // row 0..63
      const float4 v = *(const float4*)(src + (long)(kt + kl)*de.N + nt2 + ng*4);
      *(float4*)&tile[kl][ng*4] = v;
    }
  } else {
    #pragma unroll
    for (int i = 0; i < 16; ++i) {
      int idx = threadIdx.x + i*256;
      int kl = idx >> 6, nl = idx & 63;
      int k = kt + kl, n = nt2 + nl;
      tile[kl][nl] = (k < de.K && n < de.N) ? src[(long)k*de.N + n] : 0.f;
    }
  }
  __syncthreads();
  // store: ushort4 = 4 consecutive k of one n column (in-bounds: Kp,Np %64==0)
  #pragma unroll
  for (int i = 0; i < 4; ++i) {
    const int flat = threadIdx.x + i*256;
    const int kg = (flat & 7) | (((flat >> 5) & 1) << 3);      // kgroup 0..15
    const int nl = ((flat >> 3) & 3) | (((flat >> 6) & 15) << 2); // col 0..63
    ushort4 o;
    o.x = f2bf(tile[kg*4 + 0][nl]);
    o.y = f2bf(tile[kg*4 + 1][nl]);
    o.z = f2bf(tile[kg*4 + 2][nl]);
    o.w = f2bf(tile[kg*4 + 3][nl]);
    *(ushort4*)(dst + (long)(nt2 + nl)*de.Kp + kt + kg*4) = o;
  }
}

// ---------------- shared epilogue (COMPILE-TIME MR/HM — rule #20) ------------
// radd: optional row-broadcast add (v += radd[(grow%TT)*1024 + gcol]) AFTER act.
template<int MR, int HM>
__device__ __forceinline__ void epilogue_store(
    f32x4 (&acc)[MR][4], long arow0, long brow0, int wm, int wn, int lane,
    const float* bias, int biasN,
    float* Cf, int ldc, int Nf, int accum,
    u16* Cb, int ldcb, int Nb, int act, const float* radd)
{
  const int rbase = wm*HM + ((lane >> 4) << 2);
  const int cbase = wn*64 + (lane & 15);
  #pragma unroll
  for (int m = 0; m < MR; ++m) {
    #pragma unroll
    for (int n = 0; n < 4; ++n) {
      const long gcol = brow0 + cbase + n*16;
      const float bv = (bias && gcol < biasN) ? bias[gcol] : 0.f;
      #pragma unroll
      for (int r = 0; r < 4; ++r) {
        const long grow = arow0 + rbase + m*16 + r;
        float v = acc[m][n][r] + bv;
        if (act == 1) v = fmaxf(v, 0.f);
        else if (act == 2) v = (v >= 0.f) ? v : PRELU_A * v;
        if (radd) v += radd[(int)(grow % TT)*1024 + gcol];
        if (Cf && gcol < Nf) {
          const long idx = grow * (long)ldc + gcol;
          Cf[idx] = accum ? (Cf[idx] + v) : v;
        }
        if (Cb && gcol < Nb) Cb[grow * (long)ldcb + gcol] = f2bf(v);
      }
    }
  }
}

// ---------------- 64x128 bf16 GEMM, BK=64, ring-2 counted-vmcnt (R9/R11) -----
__global__ __launch_bounds__(256, 3)
void gemm64(const u16* __restrict__ A, const u16* __restrict__ Bt,
            const float* __restrict__ bias, int biasN,
            float* __restrict__ Cf, int ldc, int Nf, int accum,
            u16* __restrict__ Cb, int ldcb, int Nb,
            int K, int act, const float* __restrict__ radd)
{
  __shared__ __bf16 As[2*64*64];
  __shared__ __bf16 Bs[2*128*64];
  const int tid = threadIdx.x;
  const int wid = tid >> 6;
  const int lane = tid & 63;
  const int wm = wid >> 1, wn = wid & 1;
  int bx, by; xcd_remap(bx, by);
  const long arow0 = (long)bx * 64;
  const long brow0 = (long)by * 128;
  const int lr  = lane >> 3;
  const int lko = ((lane & 7) ^ (lane >> 3)) << 3;

  f32x4 acc[2][4];
  #pragma unroll
  for (int m = 0; m < 2; ++m)
    #pragma unroll
    for (int n = 0; n < 4; ++n) acc[m][n] = (f32x4)0.f;

  const int aro = lane & 15;
  const int g = lane >> 4;

  auto stage = [&](int buf, int kt) {
    #pragma unroll
    for (int c = wid; c < 24; c += 4) {
      if (c < 8) gload16(A + (arow0 + c*8 + lr)*K + kt + lko, As + buf*(64*64) + c*512);
      else       gload16(Bt + (brow0 + (c-8)*8 + lr)*K + kt + lko,
                         Bs + buf*(128*64) + (c-8)*512);
    }
  };

  const int nt = K >> 6;
  stage(0, 0);
  for (int t = 0; t < nt; ++t) {
    if (t + 1 < nt) {
      stage((t+1) & 1, (t+1) << 6);
      asm volatile("s_waitcnt vmcnt(6)" ::: "memory");
    } else {
      asm volatile("s_waitcnt vmcnt(0)" ::: "memory");
    }
    __builtin_amdgcn_s_barrier();
    asm volatile("" ::: "memory");
    const __bf16* Ab = As + (t&1)*(64*64);
    const __bf16* Bb = Bs + (t&1)*(128*64);
    #pragma unroll
    for (int kk = 0; kk < 2; ++kk) {
      bf16x8 af[2], bfv[4];
      #pragma unroll
      for (int m = 0; m < 2; ++m) {
        const int R = wm*32 + m*16 + aro;
        af[m] = *(const bf16x8*)(Ab + R*64 + (((kk*4 + g) ^ (R & 7)) << 3));
      }
      #pragma unroll
      for (int n = 0; n < 4; ++n) {
        const int R = wn*64 + n*16 + aro;
        bfv[n] = *(const bf16x8*)(Bb + R*64 + (((kk*4 + g) ^ (R & 7)) << 3));
      }
      #pragma unroll
      for (int m = 0; m < 2; ++m)
        #pragma unroll
        for (int n = 0; n < 4; ++n)
          acc[m][n] = __builtin_amdgcn_mfma_f32_16x16x32_bf16(af[m], bfv[n], acc[m][n], 0, 0, 0);
    }
    asm volatile("" ::: "memory");
    __builtin_amdgcn_s_barrier();    // readers done before next stage overwrites
  }
  epilogue_store<2,32>(acc, arow0, brow0, wm, wn, lane,
                       bias, biasN, Cf, ldc, Nf, accum, Cb, ldcb, Nb, act, radd);
}

// ---------------- 128x128 bf16 GEMM, BK=32, ring-2, 32KB LDS (R13) -----------
__global__ __launch_bounds__(256, 4)
void gemm128(const u16* __restrict__ A, const u16* __restrict__ Bt,
             const float* __restrict__ bias, int biasN,
             float* __restrict__ Cf, int ldc, int Nf, int accum,
             u16* __restrict__ Cb, int ldcb, int Nb,
             int K, int act)
{
  __shared__ __bf16 As[2*128*32];
  __shared__ __bf16 Bs[2*128*32];
  const int tid = threadIdx.x;
  const int wid = tid >> 6;
  const int lane = tid & 63;
  const int wm = wid >> 1, wn = wid & 1;
  int bx, by; xcd_remap(bx, by);
  const long arow0 = (long)bx * 128;
  const long brow0 = (long)by * 128;
  const int srow = lane >> 2;
  const int skoff = ((lane & 3) ^ ((lane >> 3) & 3)) << 3;

  f32x4 acc[4][4];
  #pragma unroll
  for (int m = 0; m < 4; ++m)
    #pragma unroll
    for (int n = 0; n < 4; ++n) acc[m][n] = (f32x4)0.f;

  const int aro = lane & 15;
  const int g = lane >> 4;

  auto stage = [&](int buf, int kt) {
    #pragma unroll
    for (int c = wid; c < 16; c += 4) {
      if (c < 8) gload16(A + (arow0 + c*16 + srow)*K + kt + skoff, As + buf*4096 + c*512);
      else       gload16(Bt + (brow0 + (c-8)*16 + srow)*K + kt + skoff,
                         Bs + buf*4096 + (c-8)*512);
    }
  };

  const int nt = K >> 5;
  stage(0, 0);
  for (int t = 0; t < nt; ++t) {
    if (t + 1 < nt) {
      stage((t+1) & 1, (t+1) << 5);
      asm volatile("s_waitcnt vmcnt(4)" ::: "memory");
    } else {
      asm volatile("s_waitcnt vmcnt(0)" ::: "memory");
    }
    __builtin_amdgcn_s_barrier();
    asm volatile("" ::: "memory");
    const __bf16* Ab = As + (t&1)*4096;
    const __bf16* Bb = Bs + (t&1)*4096;
    bf16x8 af[4], bfv[4];
    #pragma unroll
    for (int m = 0; m < 4; ++m) {
      const int R = wm*64 + m*16 + aro;
      af[m] = *(const bf16x8*)(Ab + R*32 + ((g ^ ((R >> 1) & 3)) << 3));
    }
    #pragma unroll
    for (int n = 0; n < 4; ++n) {
      const int R = wn*64 + n*16 + aro;
      bfv[n] = *(const bf16x8*)(Bb + R*32 + ((g ^ ((R >> 1) & 3)) << 3));
    }
    #pragma unroll
    for (int m = 0; m < 4; ++m)
      #pragma unroll
      for (int n = 0; n < 4; ++n)
        acc[m][n] = __builtin_amdgcn_mfma_f32_16x16x32_bf16(af[m], bfv[n], acc[m][n], 0, 0, 0);
    asm volatile("" ::: "memory");
    __builtin_amdgcn_s_barrier();    // readers done before next stage overwrites
  }
  epilogue_store<4,64>(acc, arow0, brow0, wm, wn, lane,
                       bias, biasN, Cf, ldc, Nf, accum, Cb, ldcb, Nb, act, nullptr);
}

// --- MoE blend (2 half-buffers, H=1024): out = prelu(sum_e gate_e * C_e) ----
__global__ __launch_bounds__(256)
void moe_blend2(const u16* __restrict__ C0, const u16* __restrict__ C1,
                const float* __restrict__ gate, u16* __restrict__ outb)
{
  const long idx = (long)blockIdx.x*256 + threadIdx.x;   // float4 over [NT,1024]
  if (idx >= (long)NT*256) return;
  const long t = idx >> 8;
  const int h = (int)(idx & 255) << 2;
  float sx = 0.f, sy = 0.f, sz = 0.f, sw = 0.f;
  #pragma unroll
  for (int j = 0; j < 4; ++j) {
    const float gv = gate[t*8 + j];
    const ushort4 c4 = *(const ushort4*)(C0 + t*4096 + j*1024 + h);
    sx += gv * bf2f(c4.x); sy += gv * bf2f(c4.y);
    sz += gv * bf2f(c4.z); sw += gv * bf2f(c4.w);
  }
  #pragma unroll
  for (int j = 0; j < 4; ++j) {
    const float gv = gate[t*8 + 4 + j];
    const ushort4 c4 = *(const ushort4*)(C1 + t*4096 + j*1024 + h);
    sx += gv * bf2f(c4.x); sy += gv * bf2f(c4.y);
    sz += gv * bf2f(c4.z); sw += gv * bf2f(c4.w);
  }
  sx = (sx >= 0.f) ? sx : PRELU_A * sx;
  sy = (sy >= 0.f) ? sy : PRELU_A * sy;
  sz = (sz >= 0.f) ? sz : PRELU_A * sz;
  sw = (sw >= 0.f) ? sw : PRELU_A * sw;
  ushort4 o; o.x = f2bf(sx); o.y = f2bf(sy); o.z = f2bf(sz); o.w = f2bf(sw);
  *(ushort4*)(outb + t*1024 + h) = o;
}

// --- MoE final blend (level 2, H=256, 8 experts contiguous) -> f32 out -------
__global__ __launch_bounds__(256)
void moe_blend_out(const u16* __restrict__ C, const float* __restrict__ gate,
                   float* __restrict__ outf)
{
  const long idx = (long)blockIdx.x*256 + threadIdx.x;   // float4 over [NT,256]
  if (idx >= (long)NT*64) return;
  const long t = idx >> 6;
  const int h = (int)(idx & 63) << 2;
  float sx = 0.f, sy = 0.f, sz = 0.f, sw = 0.f;
  #pragma unroll
  for (int j = 0; j < 8; ++j) {
    const float gv = gate[t*8 + j];
    const ushort4 c4 = *(const ushort4*)(C + t*2048 + j*256 + h);
    sx += gv * bf2f(c4.x); sy += gv * bf2f(c4.y);
    sz += gv * bf2f(c4.z); sw += gv * bf2f(c4.w);
  }
  float4 o; o.x = sx; o.y = sy; o.z = sz; o.w = sw;
  ((float4*)(outf + t*256))[h >> 2] = o;
}

// ---------------- small helper kernels --------------------------------------
__global__ __launch_bounds__(256)
void build_xin(const float* __restrict__ motion, const float* __restrict__ phase,
               u16* __restrict__ xin)   // [NT, 320] zero-padded
{
  const long idx = (long)blockIdx.x*256 + threadIdx.x;
  if (idx >= (long)NT*320) return;
  const int c = (int)(idx % 320);
  const long row = idx / 320;
  const int t = (int)(row % TT);
  const bool dm = (t < 10) || (t == TT-1);
  float v;
  if (c < 256)       v = dm ? motion[row*256 + c] : 0.f;
  else if (c == 256) v = dm ? 1.f : 0.f;
  else if (c < 273)  v = dm ? phase[row*16 + (c-257)] : 0.f;
  else               v = 0.f;
  xin[idx] = f2bf(v);
}

// kp [256,64] zero-padded + concat K/V bias [8][2048] in one launch
__global__ __launch_bounds__(256)
void build_kp_kvb(u16* __restrict__ kp,
                  const float* __restrict__ bk, const float* __restrict__ bv,
                  float* __restrict__ kvb)
{
  const int idx = blockIdx.x*256 + threadIdx.x;
  if (idx < 256*64) {
    const int r = idx / 64, c = idx % 64;
    float v = 0.f;
    if (r < TT) {
      if (c == 0) v = (float)(r - 9);
      else if (c == 1) v = (float)(TT-1 - r);
    }
    kp[idx] = f2bf(v);
  } else {
    const int j = idx - 256*64;
    if (j < 8*2048) {
      const int l = j >> 11, c = j & 2047;
      kvb[j] = (c < 1024) ? bk[l*1024 + c] : bv[l*1024 + c - 1024];
    }
  }
}

__global__ __launch_bounds__(64)
void relpos(const float* __restrict__ W1, const float* __restrict__ b1,
            const float* __restrict__ W2, const float* __restrict__ b2,
            float* __restrict__ rel)
{
  const int r = blockIdx.x;      // 0..383 (rows >=383 zeroed, never read)
  const int d = threadIdx.x;
  __shared__ float h[64];
  const float rp = (float)(r - (TT-1));
  float hv = rp * W1[d] + b1[d];
  hv = (hv >= 0.f) ? hv : PRELU_A * hv;
  h[d] = hv;
  __syncthreads();
  if (r < 2*TT - 1) {
    float o = b2[d];
    for (int j = 0; j < 64; ++j) o += h[j] * W2[j*64 + d];
    rel[r*64 + d] = o;
  } else {
    rel[r*64 + d] = 0.f;
  }
}

// LN -> bf16; optionally dual-writes keyframe rows into hk[b*11+j].
__global__ __launch_bounds__(256)
void ln_bf16(const float* __restrict__ x, const float* __restrict__ g,
             const float* __restrict__ b, u16* __restrict__ out,
             u16* __restrict__ hk)
{
  const long row = blockIdx.x;
  const float4 v = ((const float4*)(x + row*1024))[threadIdx.x];
  float s  = v.x + v.y + v.z + v.w;
  float s2 = v.x*v.x + v.y*v.y + v.z*v.z + v.w*v.w;
  #pragma unroll
  for (int m = 32; m; m >>= 1) { s += __shfl_xor(s, m); s2 += __shfl_xor(s2, m); }
  __shared__ float red[8];
  const int wid = threadIdx.x >> 6;
  if ((threadIdx.x & 63) == 0) { red[wid] = s; red[wid+4] = s2; }
  __syncthreads();
  s  = red[0] + red[1] + red[2] + red[3];
  s2 = red[4] + red[5] + red[6] + red[7];
  const float mean = s * (1.f/1024.f);
  const float var  = fmaxf(s2 * (1.f/1024.f) - mean*mean, 0.f);
  const float rs   = rsqrtf(var + 1e-5f);
  const float4 gg = ((const float4*)g)[threadIdx.x];
  const float4 bb = ((const float4*)b)[threadIdx.x];
  ushort4 o;
  o.x = f2bf((v.x-mean)*rs*gg.x + bb.x);
  o.y = f2bf((v.y-mean)*rs*gg.y + bb.y);
  o.z = f2bf((v.z-mean)*rs*gg.z + bb.z);
  o.w = f2bf((v.w-mean)*rs*gg.w + bb.w);
  ((ushort4*)(out + row*1024))[threadIdx.x] = o;
  if (hk) {
    const int t = (int)(row % TT);
    if (t < 10 || t == TT-1) {
      const int bidx = (int)(row / TT);
      const int j = (t < 10) ? t : 10;
      ((ushort4*)(hk + (long)(bidx*11 + j)*1024))[threadIdx.x] = o;
    }
  }
}

// 11-key masked attention: one BLOCK (256 thr) per row (R9-verified).
__global__ __launch_bounds__(256)
void attn11(const float* __restrict__ q, const float* __restrict__ kv,
            const float* __restrict__ rel, u16* __restrict__ o)
{
  const int row = blockIdx.x;
  const int b = row / TT, i = row - b*TT;
  const int t = threadIdx.x;
  const int n = t >> 4;         // head
  const int dq = t & 15;        // float4 slot within head
  const float4 qv = *(const float4*)(q + (long)row*1024 + t*4);
  float e[11];
  float mx = -1e30f;
  #pragma unroll
  for (int j = 0; j < 11; ++j) {
    const int kf = (j < 10) ? j : (TT-1);
    const float4 k4 = *(const float4*)(kv + (long)(b*11 + j)*2048 + n*64 + dq*4);
    const float4 r4 = *(const float4*)(rel + (kf - i + TT-1)*64 + dq*4);
    float s = qv.x*(k4.x+r4.x) + qv.y*(k4.y+r4.y)
            + qv.z*(k4.z+r4.z) + qv.w*(k4.w+r4.w);
    s += __shfl_xor(s, 1); s += __shfl_xor(s, 2);
    s += __shfl_xor(s, 4); s += __shfl_xor(s, 8);
    e[j] = s * 0.125f;           // 1/sqrt(64)
    mx = fmaxf(mx, e[j]);
  }
  float den = 0.f;
  #pragma unroll
  for (int j = 0; j < 11; ++j) { e[j] = __expf(e[j] - mx); den += e[j]; }
  const float inv = 1.f / den;
  float ax = 0.f, ay = 0.f, az = 0.f, aw = 0.f;
  #pragma unroll
  for (int j = 0; j < 11; ++j) {
    const float4 v4 = *(const float4*)(kv + (long)(b*11 + j)*2048 + 1024 + n*64 + dq*4);
    ax += e[j]*v4.x; ay += e[j]*v4.y; az += e[j]*v4.z; aw += e[j]*v4.w;
  }
  ushort4 ov;
  ov.x = f2bf(ax*inv); ov.y = f2bf(ay*inv); ov.z = f2bf(az*inv); ov.w = f2bf(aw*inv);
  *(ushort4*)(o + (long)row*1024 + t*4) = ov;
}

__global__ __launch_bounds__(256)
void softmax8(const float* __restrict__ lg, float* __restrict__ gate)
{
  const int t = blockIdx.x*256 + threadIdx.x;
  if (t >= NT) return;
  float v[8], mx = -1e30f;
  #pragma unroll
  for (int e = 0; e < 8; ++e) { v[e] = lg[t*8 + e]; mx = fmaxf(mx, v[e]); }
  float den = 0.f;
  #pragma unroll
  for (int e = 0; e < 8; ++e) { v[e] = __expf(v[e] - mx); den += v[e]; }
  const float inv = 1.f / den;
  #pragma unroll
  for (int e = 0; e < 8; ++e) gate[t*8 + e] = v[e] * inv;
}

// ---------------- host ------------------------------------------------------
extern "C" void kernel_launch(void* const* d_in, const int* in_sizes, int n_in,
                              void* d_out, int out_size, void* d_ws, size_t ws_size,
                              hipStream_t stream)
{
  (void)in_sizes; (void)n_in; (void)out_size; (void)ws_size;
  const float* motion  = (const float*)d_in[0];
  const float* phase   = (const float*)d_in[1];
  const float* enc_W1  = (const float*)d_in[2];
  const float* enc_b1  = (const float*)d_in[3];
  const float* enc_W2  = (const float*)d_in[4];
  const float* enc_b2  = (const float*)d_in[5];
  const float* kf_W1   = (const float*)d_in[6];
  const float* kf_b1   = (const float*)d_in[7];
  const float* kf_W2   = (const float*)d_in[8];
  const float* kf_b2   = (const float*)d_in[9];
  const float* rp_W1   = (const float*)d_in[10];
  const float* rp_b1   = (const float*)d_in[11];
  const float* rp_W2   = (const float*)d_in[12];
  const float* rp_b2   = (const float*)d_in[13];
  const float* att_Wq  = (const float*)d_in[14];
  const float* att_bq  = (const float*)d_in[15];
  const float* att_Wk  = (const float*)d_in[16];
  const float* att_bk  = (const float*)d_in[17];
  const float* att_Wv  = (const float*)d_in[18];
  const float* att_bv  = (const float*)d_in[19];
  const float* att_Wo  = (const float*)d_in[20];
  const float* att_bo  = (const float*)d_in[21];
  const float* att_ln_g = (const float*)d_in[22];
  const float* att_ln_b = (const float*)d_in[23];
  const float* pff_W1  = (const float*)d_in[24];
  const float* pff_b1  = (const float*)d_in[25];
  const float* pff_W2  = (const float*)d_in[26];
  const float* pff_b2  = (const float*)d_in[27];
  const float* pff_ln_g = (const float*)d_in[28];
  const float* pff_ln_b = (const float*)d_in[29];
  const float* fin_ln_g = (const float*)d_in[30];
  const float* fin_ln_b = (const float*)d_in[31];
  const float* pd_W1   = (const float*)d_in[32];
  const float* pd_b1   = (const float*)d_in[33];
  const float* pd_W2   = (const float*)d_in[34];
  const float* pd_b2   = (const float*)d_in[35];
  const float* g_W1    = (const float*)d_in[36];
  const float* g_b1    = (const float*)d_in[37];
  const float* g_W2    = (const float*)d_in[38];
  const float* g_b2    = (const float*)d_in[39];
  const float* g_W3    = (const float*)d_in[40];
  const float* g_b3    = (const float*)d_in[41];
  const float* md_W0   = (const float*)d_in[42];
  const float* md_b0   = (const float*)d_in[43];
  const float* md_W1   = (const float*)d_in[44];
  const float* md_b1   = (const float*)d_in[45];
  const float* md_W2   = (const float*)d_in[46];
  const float* md_b2   = (const float*)d_in[47];

  char* wsp = (char*)d_ws;
  size_t off = 0;
  auto alloc = [&](size_t bytes) -> char* {
    char* p = wsp + off;
    off += (bytes + 255) & ~(size_t)255;
    return p;
  };

  // bf16 transposed weights [Npad, Kpad]
  u16* encW1T = (u16*)alloc((size_t)1024*320*2);
  u16* encW2T = (u16*)alloc((size_t)1024*1024*2);
  u16* kfW1T  = (u16*)alloc((size_t)1024*64*2);
  u16* kfW2T  = (u16*)alloc((size_t)1024*1024*2);
  u16* WqT    = (u16*)alloc((size_t)8*1024*1024*2);
  u16* kvT    = (u16*)alloc((size_t)8*2048*1024*2);   // per layer: [Wk^T ; Wv^T]
  u16* WoT    = (u16*)alloc((size_t)8*1024*1024*2);
  u16* F1T    = (u16*)alloc((size_t)8*4096*1024*2);
  u16* F2T    = (u16*)alloc((size_t)8*1024*4096*2);
  u16* pdW1T  = (u16*)alloc((size_t)1024*1024*2);
  u16* pdW2T  = (u16*)alloc((size_t)128*1024*2);
  u16* gW1T   = (u16*)alloc((size_t)512*64*2);
  u16* gW2T   = (u16*)alloc((size_t)512*512*2);
  u16* gW3T   = (u16*)alloc((size_t)128*512*2);
  u16* md0T   = (u16*)alloc((size_t)8*1024*1024*2);   // [8192,1024] rows=e*1024+n
  u16* md1T   = (u16*)alloc((size_t)8*1024*1024*2);
  u16* md2T   = (u16*)alloc((size_t)8*256*1024*2);    // [2048,1024]

  // activations
  float* x    = (float*)alloc((size_t)NT*1024*4);   // residual stream
  float* rel  = (float*)alloc((size_t)384*64*4);
  u16*   kp   = (u16*)  alloc((size_t)256*64*2);
  u16*   kf1  = (u16*)  alloc((size_t)256*1024*2);
  float* kfe  = (float*)alloc((size_t)256*1024*4);
  u16*   hk   = (u16*)  alloc((size_t)384*1024*2);
  float* kvb  = (float*)alloc((size_t)8*2048*4);    // concat K/V bias
  float* kvbuf= (float*)alloc((size_t)384*2048*4);
  u16*   phbf = (u16*)  alloc((size_t)NT*64*2);
  float* glog = (float*)alloc((size_t)NT*8*4);
  float* gate = (float*)alloc((size_t)NT*8*4);
  u16*   xin  = (u16*)  alloc((size_t)NT*320*2);
  u16*   s1   = (u16*)  alloc((size_t)NT*1024*2);   // h_bf / xf_bf / y1_bf
  float* s2   = (float*)alloc((size_t)NT*1024*4);   // q f32
  u16*   s3   = (u16*)  alloc((size_t)NT*1024*2);   // o_bf / pd1 / gh1 / y0_bf
  u16*   s4   = (u16*)  alloc((size_t)NT*4096*2);   // f1_bf / gh2 / MoE C half 0
  u16*   s5   = (u16*)  alloc((size_t)NT*4096*2);   // MoE C half 1

  float* outY = (float*)d_out;              // [NT,256]
  float* outP = outY + (size_t)NT*256;      // [NT,16]

  auto g64 = [&](const u16* A, const u16* Bt, const float* bias, int biasN,
                 float* Cf, int ldc, int Nf, int accum,
                 u16* Cb, int ldcb, int Nb, int M, int K, int Npad, int act,
                 const float* radd) {
    gemm64<<<dim3(M/64, Npad/128), 256, 0, stream>>>(
        A, Bt, bias, biasN, Cf, ldc, Nf, accum, Cb, ldcb, Nb, K, act, radd);
  };
  auto g128 = [&](const u16* A, const u16* Bt, const float* bias, int biasN,
                  float* Cf, int ldc, int Nf, int accum,
                  u16* Cb, int ldcb, int Nb, int M, int K, int Npad, int act) {
    gemm128<<<dim3(M/128, Npad/128), 256, 0, stream>>>(
        A, Bt, bias, biasN, Cf, ldc, Nf, accum, Cb, ldcb, Nb, K, act);
  };

  // ---- merged weight conversion/transposition: ONE dispatch ----
  TrTable T;
  int tn = 0, toff = 0;
  auto addtr = [&](const float* s_, u16* d_, int K, int N, int Kp, int Np,
                   int batch, long dstride) {
    TrDesc& e = T.d[tn++];
    e.src = s_; e.dst = d_; e.K = K; e.N = N; e.Kp = Kp; e.Np = Np;
    e.tilesX = (Np + 63) / 64;
    e.perBatch = e.tilesX * ((Kp + 63) / 64);
    e.batch = batch; e.tileOff = toff;
    e.sstride = (long)K * N; e.dstride = dstride;
    toff += e.perBatch * batch;
  };
  addtr(enc_W1, encW1T, 273, 1024, 320, 1024, 1, (long)1024*320);
  addtr(enc_W2, encW2T, 1024, 1024, 1024, 1024, 1, (long)1024*1024);
  addtr(kf_W1,  kfW1T,  2, 1024, 64, 1024, 1, (long)1024*64);
  addtr(kf_W2,  kfW2T,  1024, 1024, 1024, 1024, 1, (long)1024*1024);
  addtr(att_Wq, WqT, 1024, 1024, 1024, 1024, 8, (long)1024*1024);
  addtr(att_Wk, kvT,                      1024, 1024, 1024, 1024, 8, (long)2048*1024);
  addtr(att_Wv, kvT + (size_t)1024*1024,  1024, 1024, 1024, 1024, 8, (long)2048*1024);
  addtr(att_Wo, WoT, 1024, 1024, 1024, 1024, 8, (long)1024*1024);
  addtr(pff_W1, F1T, 1024, 4096, 1024, 4096, 8, (long)4096*1024);
  addtr(pff_W2, F2T, 4096, 1024, 4096, 1024, 8, (long)1024*4096);
  addtr(pd_W1,  pdW1T, 1024, 1024, 1024, 1024, 1, (long)1024*1024);
  addtr(pd_W2,  pdW2T, 1024, 16, 1024, 128, 1, (long)128*1024);
  addtr(g_W1,   gW1T, 16, 512, 64, 512, 1, (long)512*64);
  addtr(g_W2,   gW2T, 512, 512, 512, 512, 1, (long)512*512);
  addtr(g_W3,   gW3T, 512, 8, 512, 128, 1, (long)128*512);
  addtr(md_W0,  md0T, 1024, 1024, 1024, 1024, 8, (long)1024*1024);
  addtr(md_W1,  md1T, 1024, 1024, 1024, 1024, 8, (long)1024*1024);
  addtr(md_W2,  md2T, 1024, 256, 1024, 256, 8, (long)256*1024);
  T.n = tn;
  transpose_all<<<toff, 256, 0, stream>>>(T);

  // ---- small precompute ----
  build_xin<<<(NT*320 + 255)/256, 256, 0, stream>>>(motion, phase, xin);
  build_kp_kvb<<<(256*64 + 8*2048 + 255)/256, 256, 0, stream>>>(kp, att_bk, att_bv, kvb);
  relpos<<<384, 64, 0, stream>>>(rp_W1, rp_b1, rp_W2, rp_b2, rel);

  // ---- keyframe embedding (before enc2: its epilogue adds kfe) ----
  g64(kp,  kfW1T, kf_b1, 1024, nullptr,0,0,0, kf1,1024,1024, 256, 64, 1024, 2, nullptr);
  g64(kf1, kfW2T, kf_b2, 1024, kfe,1024,1024,0, nullptr,0,0, 256, 1024, 1024, 0, nullptr);
  // ---- encoder (enc2 fuses + kfe[t] row-broadcast) ----
  g64(xin, encW1T, enc_b1, 1024, nullptr,0,0,0, s1,1024,1024, NT, 320, 1024, 2, nullptr);
  g64(s1,  encW2T, enc_b2, 1024, x,1024,1024,0, nullptr,0,0, NT, 1024, 1024, 2, kfe);

  // ---- transformer layers ----
  for (int l = 0; l < 8; ++l) {
    const size_t w1 = (size_t)l*1024*1024;
    const size_t wf = (size_t)l*4096*1024;
    ln_bf16<<<NT, 256, 0, stream>>>(x, att_ln_g + l*1024, att_ln_b + l*1024, s1, hk);
    g64(s1, WqT + w1, att_bq + l*1024, 1024, s2,1024,1024,0, nullptr,0,0, NT, 1024, 1024, 0, nullptr);
    g64(hk, kvT + (size_t)l*2048*1024, kvb + l*2048, 2048,
        kvbuf,2048,2048,0, nullptr,0,0, 384, 1024, 2048, 0, nullptr);
    attn11<<<NT, 256, 0, stream>>>(s2, kvbuf, rel, s3);
    g64(s3, WoT + w1, att_bo + l*1024, 1024, x,1024,1024,1, nullptr,0,0, NT, 1024, 1024, 0, nullptr);
    ln_bf16<<<NT, 256, 0, stream>>>(x, pff_ln_g + l*1024, pff_ln_b + l*1024, s1, nullptr);
    g128(s1, F1T + wf, pff_b1 + l*4096, 4096, nullptr,0,0,0, s4,4096,4096, NT, 1024, 4096, 1);
    g64(s4, F2T + wf, pff_b2 + l*1024, 1024, x,1024,1024,1, nullptr,0,0, NT, 4096, 1024, 0, nullptr);
  }

  // ---- final LN + phase decoder ----
  ln_bf16<<<NT, 256, 0, stream>>>(x, fin_ln_g, fin_ln_b, s1, nullptr);   // xf_bf
  g64(s1, pdW1T, pd_b1, 1024, nullptr,0,0,0, s3,1024,1024, NT, 1024, 1024, 2, nullptr);
  g64(s3, pdW2T, pd_b2, 16, outP,16,16,0, phbf,64,64, NT, 1024, 128, 0, nullptr);

  // ---- gating ----
  g64(phbf, gW1T, g_b1, 512, nullptr,0,0,0, s3,512,512, NT, 64, 512, 2, nullptr);
  g64(s3,   gW2T, g_b2, 512, nullptr,0,0,0, s4,512,512, NT, 512, 512, 2, nullptr);
  g64(s4,   gW3T, g_b3, 8,  glog,8,8,0, nullptr,0,0, NT, 512, 128, 0, nullptr);
  softmax8<<<(NT + 255)/256, 256, 0, stream>>>(glog, gate);

  // ---- mixture-of-experts decoder (experts concatenated along N) ----
  const int BL2 = (int)(((long)NT*256 + 255)/256);
  // level 0: x(s1) -> y0(s3)
  g128(s1, md0T,                     md_b0,        4096, nullptr,0,0,0, s4,4096,4096, NT, 1024, 4096, 0);
  g128(s1, md0T + (size_t)4096*1024, md_b0 + 4096, 4096, nullptr,0,0,0, s5,4096,4096, NT, 1024, 4096, 0);
  moe_blend2<<<BL2, 256, 0, stream>>>(s4, s5, gate, s3);
  // level 1: y0(s3) -> y1(s1)
  g128(s3, md1T,                     md_b1,        4096, nullptr,0,0,0, s4,4096,4096, NT, 1024, 4096, 0);
  g128(s3, md1T + (size_t)4096*1024, md_b1 + 4096, 4096, nullptr,0,0,0, s5,4096,4096, NT, 1024, 4096, 0);
  moe_blend2<<<BL2, 256, 0, stream>>>(s4, s5, gate, s1);
  // level 2: y1(s1) -> outY
  g128(s1, md2T, md_b2, 2048, nullptr,0,0,0, s4,2048,2048, NT, 1024, 2048, 0);
  moe_blend_out<<<(int)(((long)NT*64 + 255)/256), 256, 0, stream>>>(s4, gate, outY);
}

// Round 18
// 2785.368 us; speedup vs baseline: 1.1111x; 1.0558x over previous
//
#include <hip/hip_runtime.h>
#include <stdint.h>

typedef unsigned short u16;
typedef __attribute__((ext_vector_type(4))) float f32x4;
typedef __attribute__((ext_vector_type(8))) __bf16 bf16x8;

#define NT 6144     // B*T
#define TT 192
#define PRELU_A 0.25f

__device__ __forceinline__ u16 f2bf(float f) {
  unsigned u = __float_as_uint(f);
  u += 0x7fffu + ((u >> 16) & 1u);
  return (u16)(u >> 16);
}
__device__ __forceinline__ float bf2f(u16 u) {
  return __uint_as_float(((unsigned)u) << 16);
}

__device__ __forceinline__ void gload16(const u16* g, __bf16* l) {
  auto* l3 = reinterpret_cast<__attribute__((address_space(3))) __bf16*>(
      reinterpret_cast<uintptr_t>(l));
  const auto* g1 = reinterpret_cast<const __attribute__((address_space(1))) u16*>(
      reinterpret_cast<uintptr_t>(g));
  __builtin_amdgcn_global_load_lds(g1, l3, 16, 0, 0);
}

// m204 bijective flat remap (XCD-contiguous) + per-problem supertile decode.
__device__ __forceinline__ int remap_flat(int f, int nwg)
{
  const int q = nwg >> 3, r = nwg & 7;
  const int xcd = f & 7, s = f >> 3;
  return (xcd < r ? xcd*(q+1) : r*(q+1) + (xcd-r)*q) + s;
}
__device__ __forceinline__ void decode_st(int w, int gx, int gy, int& bx, int& by)
{
  const int CX = ((gx & 7) == 0) ? (gx >> 3) : 1;
  const int per = gy * CX;
  const int c = w / per, rr = w - c*per;
  bx = c*CX + (rr % CX);
  by = rr / CX;
}
// 2D-grid version (R14-verified behavior preserved)
__device__ __forceinline__ void xcd_remap(int& bx, int& by)
{
  const int gx = gridDim.x, gy = gridDim.y;
  const int w = remap_flat(blockIdx.y * gx + blockIdx.x, gx * gy);
  decode_st(w, gx, gy, bx, by);
}

// ---------------- merged transpose: all weights in ONE dispatch --------------
// R17: conflict-free lane remap (bank = kl_lo + 4*ng_lo bijection), float4
// loads + ushort4 stores. Kp/Np multiples of 64 -> padded dst always in-bounds.
struct TrDesc {
  const float* src; u16* dst;
  int K, N, Kp, Np;
  int tilesX, perBatch, batch, tileOff;
  long sstride, dstride;
};
struct TrTable { TrDesc d[18]; int n; };

__global__ __launch_bounds__(256)
void transpose_all(TrTable T)
{
  __shared__ float tile[64][65];
  const int bid = blockIdx.x;
  TrDesc de;
  #pragma unroll 1
  for (int i = 0; i < T.n; ++i) {
    const TrDesc& e = T.d[i];
    if (bid >= e.tileOff && bid < e.tileOff + e.perBatch * e.batch) { de = e; break; }
  }
  const int local = bid - de.tileOff;
  const int z = local / de.perBatch;
  const int rem = local - z * de.perBatch;
  const int ty = rem / de.tilesX;
  const int tx = rem - ty * de.tilesX;
  const float* src = de.src + (long)z * de.sstride;
  u16* dst = de.dst + (long)z * de.dstride;
  const int kt = ty * 64, nt2 = tx * 64;

  if (kt + 64 <= de.K && nt2 + 64 <= de.N) {
    #pragma unroll
    for (int i = 0; i < 4; ++i) {
      const int flat = threadIdx.x + i*256;
      const int ng = (flat & 7) | (((flat >> 9) & 1) << 3);
      const int kl = ((flat >> 3) & 7) | (((flat >> 6) & 7) << 3);
      const float4 v = *(const float4*)(src + (long)(kt + kl)*de.N + nt2 + ng*4);
      *(float4*)&tile[kl][ng*4] = v;
    }
  } else {
    #pragma unroll
    for (int i = 0; i < 16; ++i) {
      int idx = threadIdx.x + i*256;
      int kl = idx >> 6, nl = idx & 63;
      int k = kt + kl, n = nt2 + nl;
      tile[kl][nl] = (k < de.K && n < de.N) ? src[(long)k*de.N + n] : 0.f;
    }
  }
  __syncthreads();
  #pragma unroll
  for (int i = 0; i < 4; ++i) {
    const int flat = threadIdx.x + i*256;
    const int kg = (flat & 7) | (((flat >> 5) & 1) << 3);
    const int nl = ((flat >> 3) & 3) | (((flat >> 6) & 15) << 2);
    ushort4 o;
    o.x = f2bf(tile[kg*4 + 0][nl]);
    o.y = f2bf(tile[kg*4 + 1][nl]);
    o.z = f2bf(tile[kg*4 + 2][nl]);
    o.w = f2bf(tile[kg*4 + 3][nl]);
    *(ushort4*)(dst + (long)(nt2 + nl)*de.Kp + kt + kg*4) = o;
  }
}

// ---------------- shared epilogue (COMPILE-TIME MR/HM — rule #20) ------------
template<int MR, int HM>
__device__ __forceinline__ void epilogue_store(
    f32x4 (&acc)[MR][4], long arow0, long brow0, int wm, int wn, int lane,
    const float* bias, int biasN,
    float* Cf, int ldc, int Nf, int accum,
    u16* Cb, int ldcb, int Nb, int act, const float* radd)
{
  const int rbase = wm*HM + ((lane >> 4) << 2);
  const int cbase = wn*64 + (lane & 15);
  #pragma unroll
  for (int m = 0; m < MR; ++m) {
    #pragma unroll
    for (int n = 0; n < 4; ++n) {
      const long gcol = brow0 + cbase + n*16;
      const float bv = (bias && gcol < biasN) ? bias[gcol] : 0.f;
      #pragma unroll
      for (int r = 0; r < 4; ++r) {
        const long grow = arow0 + rbase + m*16 + r;
        float v = acc[m][n][r] + bv;
        if (act == 1) v = fmaxf(v, 0.f);
        else if (act == 2) v = (v >= 0.f) ? v : PRELU_A * v;
        if (radd) v += radd[(int)(grow % TT)*1024 + gcol];
        if (Cf && gcol < Nf) {
          const long idx = grow * (long)ldc + gcol;
          Cf[idx] = accum ? (Cf[idx] + v) : v;
        }
        if (Cb && gcol < Nb) Cb[grow * (long)ldcb + gcol] = f2bf(v);
      }
    }
  }
}

// ---------------- gemm64 core (shared by plain + QKV-merged variants) --------
__device__ __forceinline__ void gemm64_body(
    const u16* __restrict__ A, const u16* __restrict__ Bt,
    const float* __restrict__ bias, int biasN,
    float* __restrict__ Cf, int ldc, int Nf, int accum,
    u16* __restrict__ Cb, int ldcb, int Nb,
    int K, int act, const float* __restrict__ radd,
    int bx, int by, __bf16* As, __bf16* Bs)
{
  const int tid = threadIdx.x;
  const int wid = tid >> 6;
  const int lane = tid & 63;
  const int wm = wid >> 1, wn = wid & 1;
  const long arow0 = (long)bx * 64;
  const long brow0 = (long)by * 128;
  const int lr  = lane >> 3;
  const int lko = ((lane & 7) ^ (lane >> 3)) << 3;

  f32x4 acc[2][4];
  #pragma unroll
  for (int m = 0; m < 2; ++m)
    #pragma unroll
    for (int n = 0; n < 4; ++n) acc[m][n] = (f32x4)0.f;

  const int aro = lane & 15;
  const int g = lane >> 4;

  auto stage = [&](int buf, int kt) {
    #pragma unroll
    for (int c = wid; c < 24; c += 4) {
      if (c < 8) gload16(A + (arow0 + c*8 + lr)*K + kt + lko, As + buf*(64*64) + c*512);
      else       gload16(Bt + (brow0 + (c-8)*8 + lr)*K + kt + lko,
                         Bs + buf*(128*64) + (c-8)*512);
    }
  };

  const int nt = K >> 6;
  stage(0, 0);
  for (int t = 0; t < nt; ++t) {
    if (t + 1 < nt) {
      stage((t+1) & 1, (t+1) << 6);
      asm volatile("s_waitcnt vmcnt(6)" ::: "memory");
    } else {
      asm volatile("s_waitcnt vmcnt(0)" ::: "memory");
    }
    __builtin_amdgcn_s_barrier();
    asm volatile("" ::: "memory");
    const __bf16* Ab = As + (t&1)*(64*64);
    const __bf16* Bb = Bs + (t&1)*(128*64);
    #pragma unroll
    for (int kk = 0; kk < 2; ++kk) {
      bf16x8 af[2], bfv[4];
      #pragma unroll
      for (int m = 0; m < 2; ++m) {
        const int R = wm*32 + m*16 + aro;
        af[m] = *(const bf16x8*)(Ab + R*64 + (((kk*4 + g) ^ (R & 7)) << 3));
      }
      #pragma unroll
      for (int n = 0; n < 4; ++n) {
        const int R = wn*64 + n*16 + aro;
        bfv[n] = *(const bf16x8*)(Bb + R*64 + (((kk*4 + g) ^ (R & 7)) << 3));
      }
      #pragma unroll
      for (int m = 0; m < 2; ++m)
        #pragma unroll
        for (int n = 0; n < 4; ++n)
          acc[m][n] = __builtin_amdgcn_mfma_f32_16x16x32_bf16(af[m], bfv[n], acc[m][n], 0, 0, 0);
    }
    asm volatile("" ::: "memory");
    __builtin_amdgcn_s_barrier();
  }
  epilogue_store<2,32>(acc, arow0, brow0, wm, wn, lane,
                       bias, biasN, Cf, ldc, Nf, accum, Cb, ldcb, Nb, act, radd);
}

// ---------------- 64x128 bf16 GEMM, BK=64, ring-2 counted-vmcnt (R9/R11) -----
__global__ __launch_bounds__(256, 3)
void gemm64(const u16* __restrict__ A, const u16* __restrict__ Bt,
            const float* __restrict__ bias, int biasN,
            float* __restrict__ Cf, int ldc, int Nf, int accum,
            u16* __restrict__ Cb, int ldcb, int Nb,
            int K, int act, const float* __restrict__ radd)
{
  __shared__ __bf16 As[2*64*64];
  __shared__ __bf16 Bs[2*128*64];
  int bx, by; xcd_remap(bx, by);
  gemm64_body(A, Bt, bias, biasN, Cf, ldc, Nf, accum, Cb, ldcb, Nb,
              K, act, radd, bx, by, As, Bs);
}

// ---- merged Q + KV projection: one dispatch, KV blocks ride inside Q --------
// Q: A=h_bf [NT,1024] x WqT -> q_bf [NT,1024]  (gx=96, gy=8, 768 blocks)
// KV: A=hk [384,1024] x kvT -> kvbuf f32 [384,2048] (gx=6, gy=16, 96 blocks)
__global__ __launch_bounds__(256, 3)
void gemm64qkv(const u16* __restrict__ Aq, const u16* __restrict__ WqTl,
               const float* __restrict__ bq,  u16* __restrict__ qbf,
               const u16* __restrict__ Akv, const u16* __restrict__ kvTl,
               const float* __restrict__ kvbl, float* __restrict__ kvbuf)
{
  __shared__ __bf16 As[2*64*64];
  __shared__ __bf16 Bs[2*128*64];
  const int w = remap_flat(blockIdx.x, 864);     // 768 Q + 96 KV
  int bx, by;
  if (w < 768) {
    decode_st(w, 96, 8, bx, by);
    gemm64_body(Aq, WqTl, bq, 1024, nullptr, 0, 0, 0, qbf, 1024, 1024,
                1024, 0, nullptr, bx, by, As, Bs);
  } else {
    decode_st(w - 768, 6, 16, bx, by);
    gemm64_body(Akv, kvTl, kvbl, 2048, kvbuf, 2048, 2048, 0, nullptr, 0, 0,
                1024, 0, nullptr, bx, by, As, Bs);
  }
}

// ---------------- 128x128 bf16 GEMM, BK=32, ring-2, 32KB LDS (R13) -----------
// z2: when launched with gridDim.z==2, z=1 uses Bt+btoff, bias+biasN, Cb2.
__global__ __launch_bounds__(256, 4)
void gemm128(const u16* __restrict__ A, const u16* __restrict__ Bt,
             const float* __restrict__ bias, int biasN,
             float* __restrict__ Cf, int ldc, int Nf, int accum,
             u16* __restrict__ Cb, int ldcb, int Nb,
             int K, int act, long btoff, u16* __restrict__ Cb2)
{
  __shared__ __bf16 As[2*128*32];
  __shared__ __bf16 Bs[2*128*32];
  if (blockIdx.z) { Bt += btoff; bias += biasN; Cb = Cb2; }
  const int tid = threadIdx.x;
  const int wid = tid >> 6;
  const int lane = tid & 63;
  const int wm = wid >> 1, wn = wid & 1;
  int bx, by; xcd_remap(bx, by);
  const long arow0 = (long)bx * 128;
  const long brow0 = (long)by * 128;
  const int srow = lane >> 2;
  const int skoff = ((lane & 3) ^ ((lane >> 3) & 3)) << 3;

  f32x4 acc[4][4];
  #pragma unroll
  for (int m = 0; m < 4; ++m)
    #pragma unroll
    for (int n = 0; n < 4; ++n) acc[m][n] = (f32x4)0.f;

  const int aro = lane & 15;
  const int g = lane >> 4;

  auto stage = [&](int buf, int kt) {
    #pragma unroll
    for (int c = wid; c < 16; c += 4) {
      if (c < 8) gload16(A + (arow0 + c*16 + srow)*K + kt + skoff, As + buf*4096 + c*512);
      else       gload16(Bt + (brow0 + (c-8)*16 + srow)*K + kt + skoff,
                         Bs + buf*4096 + (c-8)*512);
    }
  };

  const int nt = K >> 5;
  stage(0, 0);
  for (int t = 0; t < nt; ++t) {
    if (t + 1 < nt) {
      stage((t+1) & 1, (t+1) << 5);
      asm volatile("s_waitcnt vmcnt(4)" ::: "memory");
    } else {
      asm volatile("s_waitcnt vmcnt(0)" ::: "memory");
    }
    __builtin_amdgcn_s_barrier();
    asm volatile("" ::: "memory");
    const __bf16* Ab = As + (t&1)*4096;
    const __bf16* Bb = Bs + (t&1)*4096;
    bf16x8 af[4], bfv[4];
    #pragma unroll
    for (int m = 0; m < 4; ++m) {
      const int R = wm*64 + m*16 + aro;
      af[m] = *(const bf16x8*)(Ab + R*32 + ((g ^ ((R >> 1) & 3)) << 3));
    }
    #pragma unroll
    for (int n = 0; n < 4; ++n) {
      const int R = wn*64 + n*16 + aro;
      bfv[n] = *(const bf16x8*)(Bb + R*32 + ((g ^ ((R >> 1) & 3)) << 3));
    }
    #pragma unroll
    for (int m = 0; m < 4; ++m)
      #pragma unroll
      for (int n = 0; n < 4; ++n)
        acc[m][n] = __builtin_amdgcn_mfma_f32_16x16x32_bf16(af[m], bfv[n], acc[m][n], 0, 0, 0);
    asm volatile("" ::: "memory");
    __builtin_amdgcn_s_barrier();
  }
  epilogue_store<4,64>(acc, arow0, brow0, wm, wn, lane,
                       bias, biasN, Cf, ldc, Nf, accum, Cb, ldcb, Nb, act, nullptr);
}

// --- MoE blend (2 half-buffers, H=1024): out = prelu(sum_e gate_e * C_e) ----
__global__ __launch_bounds__(256)
void moe_blend2(const u16* __restrict__ C0, const u16* __restrict__ C1,
                const float* __restrict__ gate, u16* __restrict__ outb)
{
  const long idx = (long)blockIdx.x*256 + threadIdx.x;
  if (idx >= (long)NT*256) return;
  const long t = idx >> 8;
  const int h = (int)(idx & 255) << 2;
  float sx = 0.f, sy = 0.f, sz = 0.f, sw = 0.f;
  #pragma unroll
  for (int j = 0; j < 4; ++j) {
    const float gv = gate[t*8 + j];
    const ushort4 c4 = *(const ushort4*)(C0 + t*4096 + j*1024 + h);
    sx += gv * bf2f(c4.x); sy += gv * bf2f(c4.y);
    sz += gv * bf2f(c4.z); sw += gv * bf2f(c4.w);
  }
  #pragma unroll
  for (int j = 0; j < 4; ++j) {
    const float gv = gate[t*8 + 4 + j];
    const ushort4 c4 = *(const ushort4*)(C1 + t*4096 + j*1024 + h);
    sx += gv * bf2f(c4.x); sy += gv * bf2f(c4.y);
    sz += gv * bf2f(c4.z); sw += gv * bf2f(c4.w);
  }
  sx = (sx >= 0.f) ? sx : PRELU_A * sx;
  sy = (sy >= 0.f) ? sy : PRELU_A * sy;
  sz = (sz >= 0.f) ? sz : PRELU_A * sz;
  sw = (sw >= 0.f) ? sw : PRELU_A * sw;
  ushort4 o; o.x = f2bf(sx); o.y = f2bf(sy); o.z = f2bf(sz); o.w = f2bf(sw);
  *(ushort4*)(outb + t*1024 + h) = o;
}

// --- MoE final blend (level 2, H=256, 8 experts contiguous) -> f32 out -------
__global__ __launch_bounds__(256)
void moe_blend_out(const u16* __restrict__ C, const float* __restrict__ gate,
                   float* __restrict__ outf)
{
  const long idx = (long)blockIdx.x*256 + threadIdx.x;
  if (idx >= (long)NT*64) return;
  const long t = idx >> 6;
  const int h = (int)(idx & 63) << 2;
  float sx = 0.f, sy = 0.f, sz = 0.f, sw = 0.f;
  #pragma unroll
  for (int j = 0; j < 8; ++j) {
    const float gv = gate[t*8 + j];
    const ushort4 c4 = *(const ushort4*)(C + t*2048 + j*256 + h);
    sx += gv * bf2f(c4.x); sy += gv * bf2f(c4.y);
    sz += gv * bf2f(c4.z); sw += gv * bf2f(c4.w);
  }
  float4 o; o.x = sx; o.y = sy; o.z = sz; o.w = sw;
  ((float4*)(outf + t*256))[h >> 2] = o;
}

// ---------------- small helper kernels --------------------------------------
__global__ __launch_bounds__(256)
void build_xin(const float* __restrict__ motion, const float* __restrict__ phase,
               u16* __restrict__ xin)
{
  const long idx = (long)blockIdx.x*256 + threadIdx.x;
  if (idx >= (long)NT*320) return;
  const int c = (int)(idx % 320);
  const long row = idx / 320;
  const int t = (int)(row % TT);
  const bool dm = (t < 10) || (t == TT-1);
  float v;
  if (c < 256)       v = dm ? motion[row*256 + c] : 0.f;
  else if (c == 256) v = dm ? 1.f : 0.f;
  else if (c < 273)  v = dm ? phase[row*16 + (c-257)] : 0.f;
  else               v = 0.f;
  xin[idx] = f2bf(v);
}

__global__ __launch_bounds__(256)
void build_kp_kvb(u16* __restrict__ kp,
                  const float* __restrict__ bk, const float* __restrict__ bv,
                  float* __restrict__ kvb)
{
  const int idx = blockIdx.x*256 + threadIdx.x;
  if (idx < 256*64) {
    const int r = idx / 64, c = idx % 64;
    float v = 0.f;
    if (r < TT) {
      if (c == 0) v = (float)(r - 9);
      else if (c == 1) v = (float)(TT-1 - r);
    }
    kp[idx] = f2bf(v);
  } else {
    const int j = idx - 256*64;
    if (j < 8*2048) {
      const int l = j >> 11, c = j & 2047;
      kvb[j] = (c < 1024) ? bk[l*1024 + c] : bv[l*1024 + c - 1024];
    }
  }
}

__global__ __launch_bounds__(64)
void relpos(const float* __restrict__ W1, const float* __restrict__ b1,
            const float* __restrict__ W2, const float* __restrict__ b2,
            float* __restrict__ rel)
{
  const int r = blockIdx.x;
  const int d = threadIdx.x;
  __shared__ float h[64];
  const float rp = (float)(r - (TT-1));
  float hv = rp * W1[d] + b1[d];
  hv = (hv >= 0.f) ? hv : PRELU_A * hv;
  h[d] = hv;
  __syncthreads();
  if (r < 2*TT - 1) {
    float o = b2[d];
    for (int j = 0; j < 64; ++j) o += h[j] * W2[j*64 + d];
    rel[r*64 + d] = o;
  } else {
    rel[r*64 + d] = 0.f;
  }
}

// LN -> bf16; optionally dual-writes keyframe rows into hk[b*11+j].
__global__ __launch_bounds__(256)
void ln_bf16(const float* __restrict__ x, const float* __restrict__ g,
             const float* __restrict__ b, u16* __restrict__ out,
             u16* __restrict__ hk)
{
  const long row = blockIdx.x;
  const float4 v = ((const float4*)(x + row*1024))[threadIdx.x];
  float s  = v.x + v.y + v.z + v.w;
  float s2 = v.x*v.x + v.y*v.y + v.z*v.z + v.w*v.w;
  #pragma unroll
  for (int m = 32; m; m >>= 1) { s += __shfl_xor(s, m); s2 += __shfl_xor(s2, m); }
  __shared__ float red[8];
  const int wid = threadIdx.x >> 6;
  if ((threadIdx.x & 63) == 0) { red[wid] = s; red[wid+4] = s2; }
  __syncthreads();
  s  = red[0] + red[1] + red[2] + red[3];
  s2 = red[4] + red[5] + red[6] + red[7];
  const float mean = s * (1.f/1024.f);
  const float var  = fmaxf(s2 * (1.f/1024.f) - mean*mean, 0.f);
  const float rs   = rsqrtf(var + 1e-5f);
  const float4 gg = ((const float4*)g)[threadIdx.x];
  const float4 bb = ((const float4*)b)[threadIdx.x];
  ushort4 o;
  o.x = f2bf((v.x-mean)*rs*gg.x + bb.x);
  o.y = f2bf((v.y-mean)*rs*gg.y + bb.y);
  o.z = f2bf((v.z-mean)*rs*gg.z + bb.z);
  o.w = f2bf((v.w-mean)*rs*gg.w + bb.w);
  ((ushort4*)(out + row*1024))[threadIdx.x] = o;
  if (hk) {
    const int t = (int)(row % TT);
    if (t < 10 || t == TT-1) {
      const int bidx = (int)(row / TT);
      const int j = (t < 10) ? t : 10;
      ((ushort4*)(hk + (long)(bidx*11 + j)*1024))[threadIdx.x] = o;
    }
  }
}

// 11-key masked attention: one BLOCK (256 thr) per row; q is bf16.
__global__ __launch_bounds__(256)
void attn11(const u16* __restrict__ q, const float* __restrict__ kv,
            const float* __restrict__ rel, u16* __restrict__ o)
{
  const int row = blockIdx.x;
  const int b = row / TT, i = row - b*TT;
  const int t = threadIdx.x;
  const int n = t >> 4;         // head
  const int dq = t & 15;        // float4 slot within head
  const ushort4 qu = *(const ushort4*)(q + (long)row*1024 + t*4);
  float4 qv;
  qv.x = bf2f(qu.x); qv.y = bf2f(qu.y); qv.z = bf2f(qu.z); qv.w = bf2f(qu.w);
  float e[11];
  float mx = -1e30f;
  #pragma unroll
  for (int j = 0; j < 11; ++j) {
    const int kf = (j < 10) ? j : (TT-1);
    const float4 k4 = *(const float4*)(kv + (long)(b*11 + j)*2048 + n*64 + dq*4);
    const float4 r4 = *(const float4*)(rel + (kf - i + TT-1)*64 + dq*4);
    float s = qv.x*(k4.x+r4.x) + qv.y*(k4.y+r4.y)
            + qv.z*(k4.z+r4.z) + qv.w*(k4.w+r4.w);
    s += __shfl_xor(s, 1); s += __shfl_xor(s, 2);
    s += __shfl_xor(s, 4); s += __shfl_xor(s, 8);
    e[j] = s * 0.125f;           // 1/sqrt(64)
    mx = fmaxf(mx, e[j]);
  }
  float den = 0.f;
  #pragma unroll
  for (int j = 0; j < 11; ++j) { e[j] = __expf(e[j] - mx); den += e[j]; }
  const float inv = 1.f / den;
  float ax = 0.f, ay = 0.f, az = 0.f, aw = 0.f;
  #pragma unroll
  for (int j = 0; j < 11; ++j) {
    const float4 v4 = *(const float4*)(kv + (long)(b*11 + j)*2048 + 1024 + n*64 + dq*4);
    ax += e[j]*v4.x; ay += e[j]*v4.y; az += e[j]*v4.z; aw += e[j]*v4.w;
  }
  ushort4 ov;
  ov.x = f2bf(ax*inv); ov.y = f2bf(ay*inv); ov.z = f2bf(az*inv); ov.w = f2bf(aw*inv);
  *(ushort4*)(o + (long)row*1024 + t*4) = ov;
}

__global__ __launch_bounds__(256)
void softmax8(const float* __restrict__ lg, float* __restrict__ gate)
{
  const int t = blockIdx.x*256 + threadIdx.x;
  if (t >= NT) return;
  float v[8], mx = -1e30f;
  #pragma unroll
  for (int e = 0; e < 8; ++e) { v[e] = lg[t*8 + e]; mx = fmaxf(mx, v[e]); }
  float den = 0.f;
  #pragma unroll
  for (int e = 0; e < 8; ++e) { v[e] = __expf(v[e] - mx); den += v[e]; }
  const float inv = 1.f / den;
  #pragma unroll
  for (int e = 0; e < 8; ++e) gate[t*8 + e] = v[e] * inv;
}

// ---------------- host ------------------------------------------------------
extern "C" void kernel_launch(void* const* d_in, const int* in_sizes, int n_in,
                              void* d_out, int out_size, void* d_ws, size_t ws_size,
                              hipStream_t stream)
{
  (void)in_sizes; (void)n_in; (void)out_size; (void)ws_size;
  const float* motion  = (const float*)d_in[0];
  const float* phase   = (const float*)d_in[1];
  const float* enc_W1  = (const float*)d_in[2];
  const float* enc_b1  = (const float*)d_in[3];
  const float* enc_W2  = (const float*)d_in[4];
  const float* enc_b2  = (const float*)d_in[5];
  const float* kf_W1   = (const float*)d_in[6];
  const float* kf_b1   = (const float*)d_in[7];
  const float* kf_W2   = (const float*)d_in[8];
  const float* kf_b2   = (const float*)d_in[9];
  const float* rp_W1   = (const float*)d_in[10];
  const float* rp_b1   = (const float*)d_in[11];
  const float* rp_W2   = (const float*)d_in[12];
  const float* rp_b2   = (const float*)d_in[13];
  const float* att_Wq  = (const float*)d_in[14];
  const float* att_bq  = (const float*)d_in[15];
  const float* att_Wk  = (const float*)d_in[16];
  const float* att_bk  = (const float*)d_in[17];
  const float* att_Wv  = (const float*)d_in[18];
  const float* att_bv  = (const float*)d_in[19];
  const float* att_Wo  = (const float*)d_in[20];
  const float* att_bo  = (const float*)d_in[21];
  const float* att_ln_g = (const float*)d_in[22];
  const float* att_ln_b = (const float*)d_in[23];
  const float* pff_W1  = (const float*)d_in[24];
  const float* pff_b1  = (const float*)d_in[25];
  const float* pff_W2  = (const float*)d_in[26];
  const float* pff_b2  = (const float*)d_in[27];
  const float* pff_ln_g = (const float*)d_in[28];
  const float* pff_ln_b = (const float*)d_in[29];
  const float* fin_ln_g = (const float*)d_in[30];
  const float* fin_ln_b = (const float*)d_in[31];
  const float* pd_W1   = (const float*)d_in[32];
  const float* pd_b1   = (const float*)d_in[33];
  const float* pd_W2   = (const float*)d_in[34];
  const float* pd_b2   = (const float*)d_in[35];
  const float* g_W1    = (const float*)d_in[36];
  const float* g_b1    = (const float*)d_in[37];
  const float* g_W2    = (const float*)d_in[38];
  const float* g_b2    = (const float*)d_in[39];
  const float* g_W3    = (const float*)d_in[40];
  const float* g_b3    = (const float*)d_in[41];
  const float* md_W0   = (const float*)d_in[42];
  const float* md_b0   = (const float*)d_in[43];
  const float* md_W1   = (const float*)d_in[44];
  const float* md_b1   = (const float*)d_in[45];
  const float* md_W2   = (const float*)d_in[46];
  const float* md_b2   = (const float*)d_in[47];

  char* wsp = (char*)d_ws;
  size_t off = 0;
  auto alloc = [&](size_t bytes) -> char* {
    char* p = wsp + off;
    off += (bytes + 255) & ~(size_t)255;
    return p;
  };

  // bf16 transposed weights [Npad, Kpad]
  u16* encW1T = (u16*)alloc((size_t)1024*320*2);
  u16* encW2T = (u16*)alloc((size_t)1024*1024*2);
  u16* kfW1T  = (u16*)alloc((size_t)1024*64*2);
  u16* kfW2T  = (u16*)alloc((size_t)1024*1024*2);
  u16* WqT    = (u16*)alloc((size_t)8*1024*1024*2);
  u16* kvT    = (u16*)alloc((size_t)8*2048*1024*2);
  u16* WoT    = (u16*)alloc((size_t)8*1024*1024*2);
  u16* F1T    = (u16*)alloc((size_t)8*4096*1024*2);
  u16* F2T    = (u16*)alloc((size_t)8*1024*4096*2);
  u16* pdW1T  = (u16*)alloc((size_t)1024*1024*2);
  u16* pdW2T  = (u16*)alloc((size_t)128*1024*2);
  u16* gW1T   = (u16*)alloc((size_t)512*64*2);
  u16* gW2T   = (u16*)alloc((size_t)512*512*2);
  u16* gW3T   = (u16*)alloc((size_t)128*512*2);
  u16* md0T   = (u16*)alloc((size_t)8*1024*1024*2);
  u16* md1T   = (u16*)alloc((size_t)8*1024*1024*2);
  u16* md2T   = (u16*)alloc((size_t)8*256*1024*2);

  // activations
  float* x    = (float*)alloc((size_t)NT*1024*4);
  float* rel  = (float*)alloc((size_t)384*64*4);
  u16*   kp   = (u16*)  alloc((size_t)256*64*2);
  u16*   kf1  = (u16*)  alloc((size_t)256*1024*2);
  float* kfe  = (float*)alloc((size_t)256*1024*4);
  u16*   hk   = (u16*)  alloc((size_t)384*1024*2);
  float* kvb  = (float*)alloc((size_t)8*2048*4);
  float* kvbuf= (float*)alloc((size_t)384*2048*4);
  u16*   phbf = (u16*)  alloc((size_t)NT*64*2);
  float* glog = (float*)alloc((size_t)NT*8*4);
  float* gate = (float*)alloc((size_t)NT*8*4);
  u16*   xin  = (u16*)  alloc((size_t)NT*320*2);
  u16*   s1   = (u16*)  alloc((size_t)NT*1024*2);
  u16*   qbf  = (u16*)  alloc((size_t)NT*1024*2);   // Q projection, bf16
  u16*   s3   = (u16*)  alloc((size_t)NT*1024*2);
  u16*   s4   = (u16*)  alloc((size_t)NT*4096*2);
  u16*   s5   = (u16*)  alloc((size_t)NT*4096*2);

  float* outY = (float*)d_out;              // [NT,256]
  float* outP = outY + (size_t)NT*256;      // [NT,16]

  auto g64 = [&](const u16* A, const u16* Bt, const float* bias, int biasN,
                 float* Cf, int ldc, int Nf, int accum,
                 u16* Cb, int ldcb, int Nb, int M, int K, int Npad, int act,
                 const float* radd) {
    gemm64<<<dim3(M/64, Npad/128), 256, 0, stream>>>(
        A, Bt, bias, biasN, Cf, ldc, Nf, accum, Cb, ldcb, Nb, K, act, radd);
  };
  auto g128 = [&](const u16* A, const u16* Bt, const float* bias, int biasN,
                  float* Cf, int ldc, int Nf, int accum,
                  u16* Cb, int ldcb, int Nb, int M, int K, int Npad, int act,
                  int zn, long btoff, u16* Cb2) {
    gemm128<<<dim3(M/128, Npad/128, zn), 256, 0, stream>>>(
        A, Bt, bias, biasN, Cf, ldc, Nf, accum, Cb, ldcb, Nb, K, act, btoff, Cb2);
  };

  // ---- merged weight conversion/transposition: ONE dispatch ----
  TrTable T;
  int tn = 0, toff = 0;
  auto addtr = [&](const float* s_, u16* d_, int K, int N, int Kp, int Np,
                   int batch, long dstride) {
    TrDesc& e = T.d[tn++];
    e.src = s_; e.dst = d_; e.K = K; e.N = N; e.Kp = Kp; e.Np = Np;
    e.tilesX = (Np + 63) / 64;
    e.perBatch = e.tilesX * ((Kp + 63) / 64);
    e.batch = batch; e.tileOff = toff;
    e.sstride = (long)K * N; e.dstride = dstride;
    toff += e.perBatch * batch;
  };
  addtr(enc_W1, encW1T, 273, 1024, 320, 1024, 1, (long)1024*320);
  addtr(enc_W2, encW2T, 1024, 1024, 1024, 1024, 1, (long)1024*1024);
  addtr(kf_W1,  kfW1T,  2, 1024, 64, 1024, 1, (long)1024*64);
  addtr(kf_W2,  kfW2T,  1024, 1024, 1024, 1024, 1, (long)1024*1024);
  addtr(att_Wq, WqT, 1024, 1024, 1024, 1024, 8, (long)1024*1024);
  addtr(att_Wk, kvT,                      1024, 1024, 1024, 1024, 8, (long)2048*1024);
  addtr(att_Wv, kvT + (size_t)1024*1024,  1024, 1024, 1024, 1024, 8, (long)2048*1024);
  addtr(att_Wo, WoT, 1024, 1024, 1024, 1024, 8, (long)1024*1024);
  addtr(pff_W1, F1T, 1024, 4096, 1024, 4096, 8, (long)4096*1024);
  addtr(pff_W2, F2T, 4096, 1024, 4096, 1024, 8, (long)1024*4096);
  addtr(pd_W1,  pdW1T, 1024, 1024, 1024, 1024, 1, (long)1024*1024);
  addtr(pd_W2,  pdW2T, 1024, 16, 1024, 128, 1, (long)128*1024);
  addtr(g_W1,   gW1T, 16, 512, 64, 512, 1, (long)512*64);
  addtr(g_W2,   gW2T, 512, 512, 512, 512, 1, (long)512*512);
  addtr(g_W3,   gW3T, 512, 8, 512, 128, 1, (long)128*512);
  addtr(md_W0,  md0T, 1024, 1024, 1024, 1024, 8, (long)1024*1024);
  addtr(md_W1,  md1T, 1024, 1024, 1024, 1024, 8, (long)1024*1024);
  addtr(md_W2,  md2T, 1024, 256, 1024, 256, 8, (long)256*1024);
  T.n = tn;
  transpose_all<<<toff, 256, 0, stream>>>(T);

  // ---- small precompute ----
  build_xin<<<(NT*320 + 255)/256, 256, 0, stream>>>(motion, phase, xin);
  build_kp_kvb<<<(256*64 + 8*2048 + 255)/256, 256, 0, stream>>>(kp, att_bk, att_bv, kvb);
  relpos<<<384, 64, 0, stream>>>(rp_W1, rp_b1, rp_W2, rp_b2, rel);

  // ---- keyframe embedding (before enc2: its epilogue adds kfe) ----
  g64(kp,  kfW1T, kf_b1, 1024, nullptr,0,0,0, kf1,1024,1024, 256, 64, 1024, 2, nullptr);
  g64(kf1, kfW2T, kf_b2, 1024, kfe,1024,1024,0, nullptr,0,0, 256, 1024, 1024, 0, nullptr);
  // ---- encoder (enc2 fuses + kfe[t] row-broadcast) ----
  g64(xin, encW1T, enc_b1, 1024, nullptr,0,0,0, s1,1024,1024, NT, 320, 1024, 2, nullptr);
  g64(s1,  encW2T, enc_b2, 1024, x,1024,1024,0, nullptr,0,0, NT, 1024, 1024, 2, kfe);

  // ---- transformer layers ----
  for (int l = 0; l < 8; ++l) {
    const size_t w1 = (size_t)l*1024*1024;
    const size_t wf = (size_t)l*4096*1024;
    ln_bf16<<<NT, 256, 0, stream>>>(x, att_ln_g + l*1024, att_ln_b + l*1024, s1, hk);
    gemm64qkv<<<864, 256, 0, stream>>>(
        s1, WqT + w1, att_bq + l*1024, qbf,
        hk, kvT + (size_t)l*2048*1024, kvb + l*2048, kvbuf);
    attn11<<<NT, 256, 0, stream>>>(qbf, kvbuf, rel, s3);
    g64(s3, WoT + w1, att_bo + l*1024, 1024, x,1024,1024,1, nullptr,0,0, NT, 1024, 1024, 0, nullptr);
    ln_bf16<<<NT, 256, 0, stream>>>(x, pff_ln_g + l*1024, pff_ln_b + l*1024, s1, nullptr);
    g128(s1, F1T + wf, pff_b1 + l*4096, 4096, nullptr,0,0,0, s4,4096,4096, NT, 1024, 4096, 1, 1, 0, nullptr);
    g64(s4, F2T + wf, pff_b2 + l*1024, 1024, x,1024,1024,1, nullptr,0,0, NT, 4096, 1024, 0, nullptr);
  }

  // ---- final LN + phase decoder ----
  ln_bf16<<<NT, 256, 0, stream>>>(x, fin_ln_g, fin_ln_b, s1, nullptr);
  g64(s1, pdW1T, pd_b1, 1024, nullptr,0,0,0, s3,1024,1024, NT, 1024, 1024, 2, nullptr);
  g64(s3, pdW2T, pd_b2, 16, outP,16,16,0, phbf,64,64, NT, 1024, 128, 0, nullptr);

  // ---- gating ----
  g64(phbf, gW1T, g_b1, 512, nullptr,0,0,0, s3,512,512, NT, 64, 512, 2, nullptr);
  g64(s3,   gW2T, g_b2, 512, nullptr,0,0,0, s4,512,512, NT, 512, 512, 2, nullptr);
  g64(s4,   gW3T, g_b3, 8,  glog,8,8,0, nullptr,0,0, NT, 512, 128, 0, nullptr);
  softmax8<<<(NT + 255)/256, 256, 0, stream>>>(glog, gate);

  // ---- mixture-of-experts decoder (expert halves via gridDim.z=2) ----
  const int BL2 = (int)(((long)NT*256 + 255)/256);
  // level 0: x(s1) -> y0(s3)
  g128(s1, md0T, md_b0, 4096, nullptr,0,0,0, s4,4096,4096, NT, 1024, 4096, 0,
       2, (long)4096*1024, s5);
  moe_blend2<<<BL2, 256, 0, stream>>>(s4, s5, gate, s3);
  // level 1: y0(s3) -> y1(s1)
  g128(s3, md1T, md_b1, 4096, nullptr,0,0,0, s4,4096,4096, NT, 1024, 4096, 0,
       2, (long)4096*1024, s5);
  moe_blend2<<<BL2, 256, 0, stream>>>(s4, s5, gate, s1);
  // level 2: y1(s1) -> outY
  g128(s1, md2T, md_b2, 2048, nullptr,0,0,0, s4,2048,2048, NT, 1024, 2048, 0,
       1, 0, nullptr);
  moe_blend_out<<<(int)(((long)NT*64 + 255)/256), 256, 0, stream>>>(s4, gate, outY);
}